// Round 8
// baseline (329.647 us; speedup 1.0000x reference)
//
#include <hip/hip_runtime.h>
#include <math.h>

#define N_NODES   262144
#define N_EDGES   4194304
#define NUM_GRAPHS 1024
#define NBIN      1024         // fine buckets (dst >> 8)
#define BNODE     256          // nodes per fine bucket
#define CAPB      4608         // fine bucket capacity (mean 4096, +8 sigma)
#define NCOARSE   32           // coarse buckets (dst >> 13)
#define EPBC      1024         // edges per coarse block (4KB stage -> 8 blk/CU, 2 gens)
#define EPBF      1024         // entries per fine block
#define SUBB      132          // fine sub-blocks per coarse bucket
#define CCAP      (SUBB*EPBF)  // 135168: coarse capacity (mean 131072, +11 sigma)

static __device__ __forceinline__ float fast_rcp(float v) {
    return __builtin_amdgcn_rcpf(v);
}

// ---------------------------------------------------------------------------
// K0: pack x (4f) + pos (3f) into one 32B record per node -> single 64B line
// per random src gather in the fused kernel. Runs AFTER binning (xp overlays
// the dead coarse[] buffer).
// ---------------------------------------------------------------------------
__global__ __launch_bounds__(256) void pack_kernel(
    const float* __restrict__ x, const float* __restrict__ pos,
    float* __restrict__ xp)
{
    int n = blockIdx.x * 256 + threadIdx.x;
    float4 xv = *(const float4*)(x + 4*n);
    float px = pos[3*n+0], py = pos[3*n+1], pz = pos[3*n+2];
    float4* o = (float4*)(xp + 8*n);
    o[0] = xv;
    o[1] = make_float4(px, py, pz, 0.0f);
}

// ---------------------------------------------------------------------------
// K1a: coarse radix pass. 4096 blocks x 256 thr x 1024 edges (1 int4 each).
// Small blocks (4.5KB LDS) -> 8 blocks/CU wave-capped -> 2 generations:
// the previous 4096-edge config had grid == residency (one generation), so
// kernel time == single-block serial latency. This trades batch size for
// pipelining. Write segments ~32 ints = 128B = full sector.
// ---------------------------------------------------------------------------
__global__ __launch_bounds__(256) void bin_coarse_kernel(
    const int* __restrict__ ei, int* __restrict__ cursorA,
    int* __restrict__ coarse)
{
    __shared__ int cnt[NCOARSE], rcnt[NCOARSE], lbase[NCOARSE], gbase[NCOARSE];
    __shared__ int stage[EPBC];                // 4 KB
    int tid = threadIdx.x;
    if (tid < NCOARSE) { cnt[tid] = 0; rcnt[tid] = 0; }
    __syncthreads();

    int base = blockIdx.x * EPBC;
    int4 dv = *(const int4*)(ei + N_EDGES + base + 4*tid);
    atomicAdd(&cnt[dv.x >> 13], 1);
    atomicAdd(&cnt[dv.y >> 13], 1);
    atomicAdd(&cnt[dv.z >> 13], 1);
    atomicAdd(&cnt[dv.w >> 13], 1);
    __syncthreads();

    if (tid < NCOARSE) {
        int c = cnt[tid], inc = c;
        #pragma unroll
        for (int o = 1; o < NCOARSE; o <<= 1) {
            int t = __shfl_up(inc, o);
            if (tid >= o) inc += t;
        }
        lbase[tid] = inc - c;
        gbase[tid] = c ? atomicAdd(cursorA + tid, c) : 0;
    }
    __syncthreads();

    int4 sv = *(const int4*)(ei + base + 4*tid);
    {
        int d, s, bk, r;
        d = dv.x; s = sv.x; bk = d >> 13; r = atomicAdd(&rcnt[bk], 1);
        stage[lbase[bk] + r] = ((d & 8191) << 18) | s;
        d = dv.y; s = sv.y; bk = d >> 13; r = atomicAdd(&rcnt[bk], 1);
        stage[lbase[bk] + r] = ((d & 8191) << 18) | s;
        d = dv.z; s = sv.z; bk = d >> 13; r = atomicAdd(&rcnt[bk], 1);
        stage[lbase[bk] + r] = ((d & 8191) << 18) | s;
        d = dv.w; s = sv.w; bk = d >> 13; r = atomicAdd(&rcnt[bk], 1);
        stage[lbase[bk] + r] = ((d & 8191) << 18) | s;
    }
    __syncthreads();

    // block-cooperative write-out: ~128B contiguous per bin
    for (int bk = 0; bk < NCOARSE; ++bk) {
        int c  = rcnt[bk];
        int lb = lbase[bk];
        int gb = gbase[bk];
        int lim = CCAP - gb; if (c > lim) c = lim;   // stat-impossible guard
        for (int k = tid; k < c; k += 256)
            coarse[bk*CCAP + gb + k] = stage[lb + k];
    }
}

// ---------------------------------------------------------------------------
// K1b: fine radix pass. 32 coarse x 132 sub-chunks of 1024 (4224 blocks,
// 4.5KB LDS -> 8 blk/CU, 2 generations). Coalesced scalar reads of the
// contiguous coarse slice; split into 32 fine buckets (packed bits 26..30);
// repack to ((dst&255)<<18)|src; 128B-contiguous write-out.
// ---------------------------------------------------------------------------
__global__ __launch_bounds__(256) void bin_fine_kernel(
    const int* __restrict__ cursorA, const int* __restrict__ coarse,
    int* __restrict__ cursor, int* __restrict__ staged)
{
    int tid  = threadIdx.x;
    int cb   = blockIdx.x / SUBB;
    int sub  = blockIdx.x % SUBB;
    int cntA = cursorA[cb]; if (cntA > CCAP) cntA = CCAP;
    int start = sub * EPBF;
    int n = cntA - start;
    if (n <= 0) return;                        // uniform across block
    if (n > EPBF) n = EPBF;

    __shared__ int cnt[32], rcnt[32], lbase[32], gbase[32];
    __shared__ int stage[EPBF];                // 4 KB
    if (tid < 32) { cnt[tid] = 0; rcnt[tid] = 0; }
    __syncthreads();

    const int* cptr = coarse + (size_t)cb * CCAP + start;

    for (int i = tid; i < n; i += 256)
        atomicAdd(&cnt[(cptr[i] >> 26) & 31], 1);
    __syncthreads();

    if (tid < 32) {
        int c = cnt[tid], inc = c;
        #pragma unroll
        for (int o = 1; o < 32; o <<= 1) {
            int t = __shfl_up(inc, o);
            if (tid >= o) inc += t;
        }
        lbase[tid] = inc - c;
        gbase[tid] = c ? atomicAdd(cursor + (cb*32 + tid), c) : 0;
    }
    __syncthreads();

    for (int i = tid; i < n; i += 256) {
        int p  = cptr[i];                      // L2-hot re-read
        int fb = (p >> 26) & 31;
        int r  = atomicAdd(&rcnt[fb], 1);
        stage[lbase[fb] + r] = p & 0x03FFFFFF; // ((dst&255)<<18)|src
    }
    __syncthreads();

    for (int fb = 0; fb < 32; ++fb) {
        int c  = rcnt[fb];
        int lb = lbase[fb];
        int gb = gbase[fb];
        int bkt = cb*32 + fb;
        int lim = CAPB - gb; if (c > lim) c = lim;   // ~8-sigma guard
        for (int k = tid; k < c; k += 256)
            staged[bkt*CAPB + gb + k] = stage[lb + k];
    }
}

// ---------------------------------------------------------------------------
// Per-edge contribution: rows 4..7 (x[src]) + row 8 (dist) of enc_w1, on top
// of the per-node precomputed hd[] (bias + dst rows). silu accumulate.
// ---------------------------------------------------------------------------
static __device__ __forceinline__ void edge_contrib(
    const float* __restrict__ sw1, const float* __restrict__ hd,
    float4 xs, float dist, float* __restrict__ acc)
{
    float h[16];
    #pragma unroll
    for (int j4 = 0; j4 < 4; ++j4) {
        float4 w = *(const float4*)&sw1[4*16 + 4*j4];
        h[4*j4+0] = fmaf(xs.x, w.x, hd[4*j4+0]);
        h[4*j4+1] = fmaf(xs.x, w.y, hd[4*j4+1]);
        h[4*j4+2] = fmaf(xs.x, w.z, hd[4*j4+2]);
        h[4*j4+3] = fmaf(xs.x, w.w, hd[4*j4+3]);
    }
    #pragma unroll
    for (int j4 = 0; j4 < 4; ++j4) {
        float4 w = *(const float4*)&sw1[5*16 + 4*j4];
        h[4*j4+0] = fmaf(xs.y, w.x, h[4*j4+0]);
        h[4*j4+1] = fmaf(xs.y, w.y, h[4*j4+1]);
        h[4*j4+2] = fmaf(xs.y, w.z, h[4*j4+2]);
        h[4*j4+3] = fmaf(xs.y, w.w, h[4*j4+3]);
    }
    #pragma unroll
    for (int j4 = 0; j4 < 4; ++j4) {
        float4 w = *(const float4*)&sw1[6*16 + 4*j4];
        h[4*j4+0] = fmaf(xs.z, w.x, h[4*j4+0]);
        h[4*j4+1] = fmaf(xs.z, w.y, h[4*j4+1]);
        h[4*j4+2] = fmaf(xs.z, w.z, h[4*j4+2]);
        h[4*j4+3] = fmaf(xs.z, w.w, h[4*j4+3]);
    }
    #pragma unroll
    for (int j4 = 0; j4 < 4; ++j4) {
        float4 w = *(const float4*)&sw1[7*16 + 4*j4];
        h[4*j4+0] = fmaf(xs.w, w.x, h[4*j4+0]);
        h[4*j4+1] = fmaf(xs.w, w.y, h[4*j4+1]);
        h[4*j4+2] = fmaf(xs.w, w.z, h[4*j4+2]);
        h[4*j4+3] = fmaf(xs.w, w.w, h[4*j4+3]);
    }
    #pragma unroll
    for (int j4 = 0; j4 < 4; ++j4) {
        float4 w = *(const float4*)&sw1[8*16 + 4*j4];
        h[4*j4+0] = fmaf(dist, w.x, h[4*j4+0]);
        h[4*j4+1] = fmaf(dist, w.y, h[4*j4+1]);
        h[4*j4+2] = fmaf(dist, w.z, h[4*j4+2]);
        h[4*j4+3] = fmaf(dist, w.w, h[4*j4+3]);
    }
    #pragma unroll
    for (int j = 0; j < 16; ++j) {
        float sg = fast_rcp(1.0f + __expf(-h[j]));
        acc[j] = fmaf(h[j], sg, acc[j]);
    }
}

// ---------------------------------------------------------------------------
// K2 (fused): round-4 structure, with the k-loop widened to 4 edges (8
// float4 gathers in flight per lane) -- the kernel is gather-latency-bound
// (VALU 34%, HBM 31%), so per-thread MLP is the in-kernel lever.
// VGPR budget: (256,4) caps at 128; expect ~95-110. Watch for spill (FETCH).
// ---------------------------------------------------------------------------
__global__ __launch_bounds__(256, 4) void fused_node_kernel(
    const float* __restrict__ xp,
    const int* __restrict__ cursor, const int* __restrict__ staged,
    const int* __restrict__ batch,
    const float* __restrict__ w1, const float* __restrict__ b1,
    const float* __restrict__ w2, const float* __restrict__ b2,
    const float* __restrict__ pw, const float* __restrict__ pb,
    float* __restrict__ s_out, float* __restrict__ pooled)
{
    __shared__ int esrc[CAPB];                 // 18432 B
    __shared__ int ldeg[BNODE];
    __shared__ int lcur[BNODE];
    __shared__ int wsum[4];
    __shared__ __align__(16) float sw1[144];
    __shared__ float sb1[16];
    __shared__ __align__(16) float sw2[256];
    __shared__ float sb2[16];
    __shared__ float spw[32];
    __shared__ float spb[2];

    if (threadIdx.x < 144) sw1[threadIdx.x] = w1[threadIdx.x];
    if (threadIdx.x >= 144 && threadIdx.x < 160) sb1[threadIdx.x - 144] = b1[threadIdx.x - 144];
    if (threadIdx.x >= 160 && threadIdx.x < 176) sb2[threadIdx.x - 160] = b2[threadIdx.x - 160];
    if (threadIdx.x >= 176 && threadIdx.x < 208) spw[threadIdx.x - 176] = pw[threadIdx.x - 176];
    if (threadIdx.x >= 208 && threadIdx.x < 210) spb[threadIdx.x - 208] = pb[threadIdx.x - 208];
    sw2[threadIdx.x] = w2[threadIdx.x];
    ldeg[threadIdx.x] = 0;
    __syncthreads();

    int bkt  = blockIdx.x;
    int cnt  = cursor[bkt]; if (cnt > CAPB) cnt = CAPB;
    int base = bkt * CAPB;
    int nb0  = bkt * BNODE;

    // ---- Phase A: counting sort into LDS ----
    for (int i = threadIdx.x; i < cnt; i += 256)
        atomicAdd(&ldeg[staged[base + i] >> 18], 1);
    __syncthreads();

    int dg   = ldeg[threadIdx.x];              // degree of node nb0+tid
    int lane = threadIdx.x & 63, wid = threadIdx.x >> 6;
    int inc  = dg;
    #pragma unroll
    for (int o = 1; o < 64; o <<= 1) {
        int t = __shfl_up(inc, o);
        if (lane >= o) inc += t;
    }
    if (lane == 63) wsum[wid] = inc;
    __syncthreads();
    int wb = 0;
    #pragma unroll
    for (int w = 0; w < 4; ++w) if (w < wid) wb += wsum[w];
    int r0 = wb + inc - dg;                    // exclusive row offset in esrc
    lcur[threadIdx.x] = r0;
    __syncthreads();

    for (int i = threadIdx.x; i < cnt; i += 256) {
        int p  = staged[base + i];             // L2-hot re-read
        int lo = p >> 18;
        int r  = atomicAdd(&lcur[lo], 1);
        esrc[r] = p & 0x3FFFF;
    }
    __syncthreads();

    // ---- Phase B: per-node gather + edge MLP ----
    int n = nb0 + threadIdx.x;
    const float4* xp4 = (const float4*)xp;
    float4 xd = xp4[2*n];
    float4 pd = xp4[2*n+1];

    // hd[j] = b1[j] + sum_{i<4} xd_i * w1[i][j]  -- hoisted out of edge loop
    float hd[16];
    #pragma unroll
    for (int j = 0; j < 16; ++j) hd[j] = sb1[j];
    #pragma unroll
    for (int j4 = 0; j4 < 4; ++j4) {
        float4 w0 = *(const float4*)&sw1[0*16 + 4*j4];
        float4 w1r = *(const float4*)&sw1[1*16 + 4*j4];
        float4 w2r = *(const float4*)&sw1[2*16 + 4*j4];
        float4 w3r = *(const float4*)&sw1[3*16 + 4*j4];
        hd[4*j4+0] = fmaf(xd.x, w0.x, hd[4*j4+0]);
        hd[4*j4+1] = fmaf(xd.x, w0.y, hd[4*j4+1]);
        hd[4*j4+2] = fmaf(xd.x, w0.z, hd[4*j4+2]);
        hd[4*j4+3] = fmaf(xd.x, w0.w, hd[4*j4+3]);
        hd[4*j4+0] = fmaf(xd.y, w1r.x, hd[4*j4+0]);
        hd[4*j4+1] = fmaf(xd.y, w1r.y, hd[4*j4+1]);
        hd[4*j4+2] = fmaf(xd.y, w1r.z, hd[4*j4+2]);
        hd[4*j4+3] = fmaf(xd.y, w1r.w, hd[4*j4+3]);
        hd[4*j4+0] = fmaf(xd.z, w2r.x, hd[4*j4+0]);
        hd[4*j4+1] = fmaf(xd.z, w2r.y, hd[4*j4+1]);
        hd[4*j4+2] = fmaf(xd.z, w2r.z, hd[4*j4+2]);
        hd[4*j4+3] = fmaf(xd.z, w2r.w, hd[4*j4+3]);
        hd[4*j4+0] = fmaf(xd.w, w3r.x, hd[4*j4+0]);
        hd[4*j4+1] = fmaf(xd.w, w3r.y, hd[4*j4+1]);
        hd[4*j4+2] = fmaf(xd.w, w3r.z, hd[4*j4+2]);
        hd[4*j4+3] = fmaf(xd.w, w3r.w, hd[4*j4+3]);
    }

    float acc[16];
    #pragma unroll
    for (int j = 0; j < 16; ++j) acc[j] = 0.0f;

    int k = 0;
    for (; k + 4 <= dg; k += 4) {
        int s0 = esrc[r0 + k];
        int s1 = esrc[r0 + k + 1];
        int s2 = esrc[r0 + k + 2];
        int s3 = esrc[r0 + k + 3];
        float4 a0 = xp4[2*s0], p0 = xp4[2*s0+1];
        float4 a1 = xp4[2*s1], p1 = xp4[2*s1+1];
        float4 a2 = xp4[2*s2], p2 = xp4[2*s2+1];
        float4 a3 = xp4[2*s3], p3 = xp4[2*s3+1];

        float dx0 = p0.x - pd.x, dy0 = p0.y - pd.y, dz0 = p0.z - pd.z;
        float dist0 = sqrtf(fmaf(dx0, dx0, fmaf(dy0, dy0, dz0*dz0)));
        edge_contrib(sw1, hd, a0, dist0, acc);

        float dx1 = p1.x - pd.x, dy1 = p1.y - pd.y, dz1 = p1.z - pd.z;
        float dist1 = sqrtf(fmaf(dx1, dx1, fmaf(dy1, dy1, dz1*dz1)));
        edge_contrib(sw1, hd, a1, dist1, acc);

        float dx2 = p2.x - pd.x, dy2 = p2.y - pd.y, dz2 = p2.z - pd.z;
        float dist2 = sqrtf(fmaf(dx2, dx2, fmaf(dy2, dy2, dz2*dz2)));
        edge_contrib(sw1, hd, a2, dist2, acc);

        float dx3 = p3.x - pd.x, dy3 = p3.y - pd.y, dz3 = p3.z - pd.z;
        float dist3 = sqrtf(fmaf(dx3, dx3, fmaf(dy3, dy3, dz3*dz3)));
        edge_contrib(sw1, hd, a3, dist3, acc);
    }
    for (; k < dg; ++k) {
        int s0 = esrc[r0 + k];
        float4 a0 = xp4[2*s0], p0 = xp4[2*s0+1];
        float dx0 = p0.x - pd.x, dy0 = p0.y - pd.y, dz0 = p0.z - pd.z;
        float dist0 = sqrtf(fmaf(dx0, dx0, fmaf(dy0, dy0, dz0*dz0)));
        edge_contrib(sw1, hd, a0, dist0, acc);
    }

    // ---- Phase C: node MLP + softmax + pooling ----
    float c = (float)dg;
    float inv = fast_rcp(fmaxf(c, 1.0f));
    float h[16];
    #pragma unroll
    for (int j = 0; j < 16; ++j) h[j] = c * sb2[j];
    #pragma unroll
    for (int i = 0; i < 16; ++i) {
        float f = acc[i];
        #pragma unroll
        for (int j4 = 0; j4 < 4; ++j4) {
            float4 w = *(const float4*)&sw2[i*16 + 4*j4];
            h[4*j4+0] = fmaf(f, w.x, h[4*j4+0]);
            h[4*j4+1] = fmaf(f, w.y, h[4*j4+1]);
            h[4*j4+2] = fmaf(f, w.z, h[4*j4+2]);
            h[4*j4+3] = fmaf(f, w.w, h[4*j4+3]);
        }
    }
    #pragma unroll
    for (int j = 0; j < 16; ++j) h[j] = fmaxf(h[j] * inv, 0.0f);

    float l0 = spb[0], l1 = spb[1];
    #pragma unroll
    for (int j = 0; j < 16; ++j) {
        l0 = fmaf(h[j], spw[2*j+0], l0);
        l1 = fmaf(h[j], spw[2*j+1], l1);
    }
    float m = fmaxf(l0, l1);
    float e0 = __expf(l0 - m), e1 = __expf(l1 - m);
    float r = fast_rcp(e0 + e1);
    float s0 = e0 * r, s1 = e1 * r;
    s_out[2*n+0] = s0;
    s_out[2*n+1] = s1;

    float w[32];
    #pragma unroll
    for (int j = 0; j < 16; ++j) { w[j] = s0 * h[j]; w[16+j] = s1 * h[j]; }

    int b = batch[n];
    #pragma unroll
    for (int o = 1; o < 64; o <<= 1) {
        int bn = __shfl_down(b, o);
        bool take = (lane + o < 64) && (bn == b);
        #pragma unroll
        for (int cc = 0; cc < 32; ++cc) {
            float vn = __shfl_down(w[cc], o);
            if (take) w[cc] += vn;
        }
    }
    int bp = __shfl_up(b, 1);
    if (lane == 0 || bp != b) {
        float* pg = pooled + 32*b;
        #pragma unroll
        for (int cc = 0; cc < 32; ++cc) unsafeAtomicAdd(pg + cc, w[cc]);
    }
}

// ---------------------------------------------------------------------------
// K3: per-graph heads. z, recon, analytic potential + forces.
// ---------------------------------------------------------------------------
__global__ __launch_bounds__(256) void graph_kernel(
    const float* __restrict__ pooled,
    const float* __restrict__ toz_w, const float* __restrict__ toz_b,
    const float* __restrict__ vp_w1, const float* __restrict__ vp_b1,
    const float* __restrict__ vp_w2, const float* __restrict__ vp_b2,
    const float* __restrict__ bridge_w, const float* __restrict__ bridge_b,
    float* __restrict__ out_recon, float* __restrict__ out_z,
    float* __restrict__ out_forces, float* __restrict__ out_V)
{
    int g = blockIdx.x * 256 + threadIdx.x;
    if (g >= NUM_GRAPHS) return;

    const float* P = pooled + 32*g;
    float z[8];
    #pragma unroll
    for (int k = 0; k < 2; ++k) {
        #pragma unroll
        for (int d = 0; d < 4; ++d) {
            float a = toz_b[d];
            #pragma unroll
            for (int i = 0; i < 16; ++i) a = fmaf(P[16*k+i], toz_w[4*i+d], a);
            z[4*k+d] = a;
        }
    }
    #pragma unroll
    for (int i = 0; i < 8; ++i) out_z[8*g+i] = z[i];

    #pragma unroll
    for (int j = 0; j < 32; ++j) {
        float a = bridge_b[j];
        #pragma unroll
        for (int i = 0; i < 8; ++i) a = fmaf(z[i], bridge_w[32*i+j], a);
        out_recon[32*g+j] = a;
    }

    float d0 = z[0]-z[4], d1 = z[1]-z[5];
    float dd = sqrtf(d0*d0 + d1*d1 + 1e-6f);

    float V = vp_b2[0];
    float dV = 0.0f;
    #pragma unroll
    for (int j = 0; j < 32; ++j) {
        float w1 = vp_w1[j];
        float t  = fmaf(dd, w1, vp_b1[j]);
        float et = __expf(t);
        float sp = __logf(1.0f + et);
        float sg = et / (1.0f + et);
        float w2 = vp_w2[j];
        V  = fmaf(sp, w2, V);
        dV = fmaf(sg * w1, w2, dV);
    }
    out_V[g] = V;

    float scale = dV / dd;
    float gx = scale * d0, gy = scale * d1;
    out_forces[4*g+0] = -gx;
    out_forces[4*g+1] = -gy;
    out_forces[4*g+2] =  gx;
    out_forces[4*g+3] =  gy;
}

// ---------------------------------------------------------------------------
extern "C" void kernel_launch(void* const* d_in, const int* in_sizes, int n_in,
                              void* d_out, int out_size, void* d_ws, size_t ws_size,
                              hipStream_t stream) {
    const float* x        = (const float*)d_in[0];
    const float* pos      = (const float*)d_in[1];
    const int*   ei       = (const int*)  d_in[2];
    const int*   batch    = (const int*)  d_in[3];
    const float* enc_w1   = (const float*)d_in[4];
    const float* enc_b1   = (const float*)d_in[5];
    const float* enc_w2   = (const float*)d_in[6];
    const float* enc_b2   = (const float*)d_in[7];
    const float* pool_w   = (const float*)d_in[8];
    const float* pool_b   = (const float*)d_in[9];
    const float* toz_w    = (const float*)d_in[10];
    const float* toz_b    = (const float*)d_in[11];
    const float* vp_w1    = (const float*)d_in[12];
    const float* vp_b1    = (const float*)d_in[13];
    const float* vp_w2    = (const float*)d_in[14];
    const float* vp_b2    = (const float*)d_in[15];
    const float* bridge_w = (const float*)d_in[16];
    const float* bridge_b = (const float*)d_in[17];

    // workspace layout (4B units), ~36.3 MB; xp overlays dead coarse[]
    int*   cursorA = (int*)d_ws;                                  // 32
    int*   cursor  = cursorA + NCOARSE;                           // 1024
    float* pooled  = (float*)(cursor + NBIN);                     // 32768
    int*   staged  = (int*)pooled + 32768;                        // 1024*4608
    int*   coarse  = staged + (size_t)NBIN*CAPB;                  // 32*135168
    float* xp      = (float*)coarse;                              // 2097152 (alias)

    float* out        = (float*)d_out;
    float* out_recon  = out;                        // 1024*32
    float* out_z      = out_recon + 1024*32;        // 1024*8
    float* out_s      = out_z + 1024*8;             // 262144*2
    float* out_forces = out_s + (size_t)N_NODES*2;  // 1024*4
    float* out_V      = out_forces + 1024*4;        // 1024

    hipMemsetAsync(d_ws, 0, (size_t)(NCOARSE + NBIN + 32768) * sizeof(float), stream);

    bin_coarse_kernel<<<N_EDGES/EPBC, 256, 0, stream>>>(ei, cursorA, coarse);
    bin_fine_kernel  <<<NCOARSE*SUBB, 256, 0, stream>>>(cursorA, coarse, cursor, staged);
    pack_kernel      <<<N_NODES/256, 256, 0, stream>>>(x, pos, xp);
    fused_node_kernel<<<NBIN, 256, 0, stream>>>(
        xp, cursor, staged, batch,
        enc_w1, enc_b1, enc_w2, enc_b2, pool_w, pool_b, out_s, pooled);
    graph_kernel<<<NUM_GRAPHS/256, 256, 0, stream>>>(
        pooled, toz_w, toz_b, vp_w1, vp_b1, vp_w2, vp_b2,
        bridge_w, bridge_b, out_recon, out_z, out_forces, out_V);
}

// Round 9
// 288.342 us; speedup vs baseline: 1.1432x; 1.1432x over previous
//
#include <hip/hip_runtime.h>
#include <math.h>

#define N_NODES   262144
#define N_EDGES   4194304
#define NUM_GRAPHS 1024
#define NBKT      256          // buckets (dst >> 10), 1024 nodes each
#define BNODE     256          // nodes per fused block (quarter bucket)
#define CAPK      17408        // bucket capacity (mean 16384, +8 sigma)
#define CAPB      4608         // per-quarter esrc capacity (mean 4096, +8 sigma)
#define EPB       8192         // edges per binning block

static __device__ __forceinline__ float fast_rcp(float v) {
    return __builtin_amdgcn_rcpf(v);
}

// ---------------------------------------------------------------------------
// K1: one-pass binning into 256 buckets + node packing fused in.
// 512 blocks x 256 thr x 32 edges. LDS-staged scatter: per-block per-bin
// segments ~32 ints = 128B = full L2 sector. Cursor atomics: 512 blocks x
// 256 addrs = 512 serialized per addr (r8 showed 4096/addr is the cliff).
// Each block also packs 512 nodes of xp (x|pos 32B records) -- independent
// work replacing the separate pack kernel.
// One pass replaces the r6/r7 two-pass radix: per-pass cost was ~75-90us
// and invariant to structure, so pass count is the only lever left.
// ---------------------------------------------------------------------------
__global__ __launch_bounds__(256) void bin_pack_kernel(
    const int* __restrict__ ei, const float* __restrict__ x,
    const float* __restrict__ pos,
    int* __restrict__ cursor, int* __restrict__ staged,
    float* __restrict__ xp)
{
    __shared__ int cnt[NBKT], rcnt[NBKT], lbase[NBKT], gbase[NBKT];
    __shared__ int stage[EPB];                 // 32 KB
    __shared__ int wsum[4];
    int tid = threadIdx.x;
    cnt[tid] = 0; rcnt[tid] = 0;
    __syncthreads();

    // ---- pack 512 nodes (2 per thread), independent of edge work ----
    {
        int n0 = blockIdx.x * 512 + tid;
        int n1 = n0 + 256;
        float4 xv0 = *(const float4*)(x + 4*n0);
        float4 xv1 = *(const float4*)(x + 4*n1);
        float4 pv0 = make_float4(pos[3*n0+0], pos[3*n0+1], pos[3*n0+2], 0.0f);
        float4 pv1 = make_float4(pos[3*n1+0], pos[3*n1+1], pos[3*n1+2], 0.0f);
        float4* o0 = (float4*)(xp + 8*n0);
        float4* o1 = (float4*)(xp + 8*n1);
        o0[0] = xv0; o0[1] = pv0;
        o1[0] = xv1; o1[1] = pv1;
    }

    // ---- histogram (dst kept in regs for the rank pass) ----
    int base = blockIdx.x * EPB;
    const int4* d4 = (const int4*)(ei + N_EDGES + base);
    const int4* s4 = (const int4*)(ei + base);
    int4 dv[8];
    #pragma unroll
    for (int i = 0; i < 8; ++i) {
        dv[i] = d4[i*256 + tid];
        atomicAdd(&cnt[dv[i].x >> 10], 1);
        atomicAdd(&cnt[dv[i].y >> 10], 1);
        atomicAdd(&cnt[dv[i].z >> 10], 1);
        atomicAdd(&cnt[dv[i].w >> 10], 1);
    }
    __syncthreads();

    // ---- local exclusive scan (1 bin/thread) + global cursor alloc ----
    int c = cnt[tid];
    int lane = tid & 63, wid = tid >> 6;
    int inc = c;
    #pragma unroll
    for (int o = 1; o < 64; o <<= 1) {
        int t = __shfl_up(inc, o);
        if (lane >= o) inc += t;
    }
    if (lane == 63) wsum[wid] = inc;
    __syncthreads();
    int wb = 0;
    #pragma unroll
    for (int w = 0; w < 4; ++w) if (w < wid) wb += wsum[w];
    lbase[tid] = wb + inc - c;
    gbase[tid] = c ? atomicAdd(cursor + tid, c) : 0;
    __syncthreads();

    // ---- rank + stage: ((dst&1023)<<18) | src ----
    #pragma unroll
    for (int i = 0; i < 8; ++i) {
        int4 sv = s4[i*256 + tid];
        int d, s, bk, r;
        d = dv[i].x; s = sv.x; bk = d >> 10; r = atomicAdd(&rcnt[bk], 1);
        stage[lbase[bk] + r] = ((d & 1023) << 18) | s;
        d = dv[i].y; s = sv.y; bk = d >> 10; r = atomicAdd(&rcnt[bk], 1);
        stage[lbase[bk] + r] = ((d & 1023) << 18) | s;
        d = dv[i].z; s = sv.z; bk = d >> 10; r = atomicAdd(&rcnt[bk], 1);
        stage[lbase[bk] + r] = ((d & 1023) << 18) | s;
        d = dv[i].w; s = sv.w; bk = d >> 10; r = atomicAdd(&rcnt[bk], 1);
        stage[lbase[bk] + r] = ((d & 1023) << 18) | s;
    }
    __syncthreads();

    // ---- write-out: 32 lanes per bin, ~128B contiguous segments ----
    int sub = tid & 31;
    int grp = tid >> 5;                        // 8 groups of 32 lanes
    #pragma unroll
    for (int pass = 0; pass < NBKT/8; ++pass) {
        int bk  = pass*8 + grp;
        int c2  = rcnt[bk];
        int lb  = lbase[bk];
        int gb  = gbase[bk];
        int lim = CAPK - gb; if (c2 > lim) c2 = lim;   // ~8-sigma guard
        for (int k = sub; k < c2; k += 32)
            staged[bk*CAPK + gb + k] = stage[lb + k];
    }
}

// ---------------------------------------------------------------------------
// Per-edge contribution: rows 4..7 (x[src]) + row 8 (dist) of enc_w1, on top
// of the per-node precomputed hd[] (bias + dst rows). silu accumulate.
// ---------------------------------------------------------------------------
static __device__ __forceinline__ void edge_contrib(
    const float* __restrict__ sw1, const float* __restrict__ hd,
    float4 xs, float dist, float* __restrict__ acc)
{
    float h[16];
    #pragma unroll
    for (int j4 = 0; j4 < 4; ++j4) {
        float4 w = *(const float4*)&sw1[4*16 + 4*j4];
        h[4*j4+0] = fmaf(xs.x, w.x, hd[4*j4+0]);
        h[4*j4+1] = fmaf(xs.x, w.y, hd[4*j4+1]);
        h[4*j4+2] = fmaf(xs.x, w.z, hd[4*j4+2]);
        h[4*j4+3] = fmaf(xs.x, w.w, hd[4*j4+3]);
    }
    #pragma unroll
    for (int j4 = 0; j4 < 4; ++j4) {
        float4 w = *(const float4*)&sw1[5*16 + 4*j4];
        h[4*j4+0] = fmaf(xs.y, w.x, h[4*j4+0]);
        h[4*j4+1] = fmaf(xs.y, w.y, h[4*j4+1]);
        h[4*j4+2] = fmaf(xs.y, w.z, h[4*j4+2]);
        h[4*j4+3] = fmaf(xs.y, w.w, h[4*j4+3]);
    }
    #pragma unroll
    for (int j4 = 0; j4 < 4; ++j4) {
        float4 w = *(const float4*)&sw1[6*16 + 4*j4];
        h[4*j4+0] = fmaf(xs.z, w.x, h[4*j4+0]);
        h[4*j4+1] = fmaf(xs.z, w.y, h[4*j4+1]);
        h[4*j4+2] = fmaf(xs.z, w.z, h[4*j4+2]);
        h[4*j4+3] = fmaf(xs.z, w.w, h[4*j4+3]);
    }
    #pragma unroll
    for (int j4 = 0; j4 < 4; ++j4) {
        float4 w = *(const float4*)&sw1[7*16 + 4*j4];
        h[4*j4+0] = fmaf(xs.w, w.x, h[4*j4+0]);
        h[4*j4+1] = fmaf(xs.w, w.y, h[4*j4+1]);
        h[4*j4+2] = fmaf(xs.w, w.z, h[4*j4+2]);
        h[4*j4+3] = fmaf(xs.w, w.w, h[4*j4+3]);
    }
    #pragma unroll
    for (int j4 = 0; j4 < 4; ++j4) {
        float4 w = *(const float4*)&sw1[8*16 + 4*j4];
        h[4*j4+0] = fmaf(dist, w.x, h[4*j4+0]);
        h[4*j4+1] = fmaf(dist, w.y, h[4*j4+1]);
        h[4*j4+2] = fmaf(dist, w.z, h[4*j4+2]);
        h[4*j4+3] = fmaf(dist, w.w, h[4*j4+3]);
    }
    #pragma unroll
    for (int j = 0; j < 16; ++j) {
        float sg = fast_rcp(1.0f + __expf(-h[j]));
        acc[j] = fmaf(h[j], sg, acc[j]);
    }
}

// ---------------------------------------------------------------------------
// K2 (fused): round-7 known-good core (112us). 1024 blocks; block bid owns
// quarter q=bid&3 of bucket cb=bid>>2 (nodes bid*256..+256). Phase A filters
// the bucket's staged entries by quarter (staged is L3-resident; 4x re-read
// is Infinity-Cache-hot). Phase B/C byte-identical to round 7 (2-wide loop;
// 4-wide spilled in r8: VGPR pinned 64, +41MB FETCH / +42MB WRITE scratch).
// ---------------------------------------------------------------------------
__global__ __launch_bounds__(256, 4) void fused_node_kernel(
    const float* __restrict__ xp,
    const int* __restrict__ cursor, const int* __restrict__ staged,
    const int* __restrict__ batch,
    const float* __restrict__ w1, const float* __restrict__ b1,
    const float* __restrict__ w2, const float* __restrict__ b2,
    const float* __restrict__ pw, const float* __restrict__ pb,
    float* __restrict__ s_out, float* __restrict__ pooled)
{
    __shared__ int esrc[CAPB];                 // 18432 B
    __shared__ int ldeg[BNODE];
    __shared__ int lcur[BNODE];
    __shared__ int wsum[4];
    __shared__ __align__(16) float sw1[144];
    __shared__ float sb1[16];
    __shared__ __align__(16) float sw2[256];
    __shared__ float sb2[16];
    __shared__ float spw[32];
    __shared__ float spb[2];

    if (threadIdx.x < 144) sw1[threadIdx.x] = w1[threadIdx.x];
    if (threadIdx.x >= 144 && threadIdx.x < 160) sb1[threadIdx.x - 144] = b1[threadIdx.x - 144];
    if (threadIdx.x >= 160 && threadIdx.x < 176) sb2[threadIdx.x - 160] = b2[threadIdx.x - 160];
    if (threadIdx.x >= 176 && threadIdx.x < 208) spw[threadIdx.x - 176] = pw[threadIdx.x - 176];
    if (threadIdx.x >= 208 && threadIdx.x < 210) spb[threadIdx.x - 208] = pb[threadIdx.x - 208];
    sw2[threadIdx.x] = w2[threadIdx.x];
    ldeg[threadIdx.x] = 0;
    __syncthreads();

    int cb   = blockIdx.x >> 2;                // coarse bucket
    int q    = blockIdx.x & 3;                 // quarter (lo bits 8..9)
    int cnt  = cursor[cb]; if (cnt > CAPK) cnt = CAPK;
    int base = cb * CAPK;
    int nb0  = blockIdx.x * BNODE;             // = cb*1024 + q*256

    // ---- Phase A: quarter-filtered counting sort into LDS ----
    for (int i = threadIdx.x; i < cnt; i += 256) {
        int lo = staged[base + i] >> 18;
        if ((lo >> 8) == q) atomicAdd(&ldeg[lo & 255], 1);
    }
    __syncthreads();

    int dg   = ldeg[threadIdx.x];              // degree of node nb0+tid
    int lane = threadIdx.x & 63, wid = threadIdx.x >> 6;
    int inc  = dg;
    #pragma unroll
    for (int o = 1; o < 64; o <<= 1) {
        int t = __shfl_up(inc, o);
        if (lane >= o) inc += t;
    }
    if (lane == 63) wsum[wid] = inc;
    __syncthreads();
    int wb = 0;
    #pragma unroll
    for (int w = 0; w < 4; ++w) if (w < wid) wb += wsum[w];
    int r0 = wb + inc - dg;                    // exclusive row offset in esrc
    lcur[threadIdx.x] = r0;
    __syncthreads();

    for (int i = threadIdx.x; i < cnt; i += 256) {
        int p  = staged[base + i];             // L3-hot re-read
        int lo = p >> 18;
        if ((lo >> 8) == q) {
            int r = atomicAdd(&lcur[lo & 255], 1);
            if (r < CAPB) esrc[r] = p & 0x3FFFF;
        }
    }
    __syncthreads();

    // ---- Phase B: per-node gather + edge MLP (r7 verbatim) ----
    int n = nb0 + threadIdx.x;
    const float4* xp4 = (const float4*)xp;
    float4 xd = xp4[2*n];
    float4 pd = xp4[2*n+1];

    // hd[j] = b1[j] + sum_{i<4} xd_i * w1[i][j]  -- hoisted out of edge loop
    float hd[16];
    #pragma unroll
    for (int j = 0; j < 16; ++j) hd[j] = sb1[j];
    #pragma unroll
    for (int j4 = 0; j4 < 4; ++j4) {
        float4 w0 = *(const float4*)&sw1[0*16 + 4*j4];
        float4 w1r = *(const float4*)&sw1[1*16 + 4*j4];
        float4 w2r = *(const float4*)&sw1[2*16 + 4*j4];
        float4 w3r = *(const float4*)&sw1[3*16 + 4*j4];
        hd[4*j4+0] = fmaf(xd.x, w0.x, hd[4*j4+0]);
        hd[4*j4+1] = fmaf(xd.x, w0.y, hd[4*j4+1]);
        hd[4*j4+2] = fmaf(xd.x, w0.z, hd[4*j4+2]);
        hd[4*j4+3] = fmaf(xd.x, w0.w, hd[4*j4+3]);
        hd[4*j4+0] = fmaf(xd.y, w1r.x, hd[4*j4+0]);
        hd[4*j4+1] = fmaf(xd.y, w1r.y, hd[4*j4+1]);
        hd[4*j4+2] = fmaf(xd.y, w1r.z, hd[4*j4+2]);
        hd[4*j4+3] = fmaf(xd.y, w1r.w, hd[4*j4+3]);
        hd[4*j4+0] = fmaf(xd.z, w2r.x, hd[4*j4+0]);
        hd[4*j4+1] = fmaf(xd.z, w2r.y, hd[4*j4+1]);
        hd[4*j4+2] = fmaf(xd.z, w2r.z, hd[4*j4+2]);
        hd[4*j4+3] = fmaf(xd.z, w2r.w, hd[4*j4+3]);
        hd[4*j4+0] = fmaf(xd.w, w3r.x, hd[4*j4+0]);
        hd[4*j4+1] = fmaf(xd.w, w3r.y, hd[4*j4+1]);
        hd[4*j4+2] = fmaf(xd.w, w3r.z, hd[4*j4+2]);
        hd[4*j4+3] = fmaf(xd.w, w3r.w, hd[4*j4+3]);
    }

    float acc[16];
    #pragma unroll
    for (int j = 0; j < 16; ++j) acc[j] = 0.0f;

    int k = 0;
    for (; k + 2 <= dg; k += 2) {
        int s0 = esrc[r0 + k];
        int s1 = esrc[r0 + k + 1];
        float4 a0 = xp4[2*s0], p0 = xp4[2*s0+1];
        float4 a1 = xp4[2*s1], p1 = xp4[2*s1+1];

        float dx0 = p0.x - pd.x, dy0 = p0.y - pd.y, dz0 = p0.z - pd.z;
        float dist0 = sqrtf(fmaf(dx0, dx0, fmaf(dy0, dy0, dz0*dz0)));
        edge_contrib(sw1, hd, a0, dist0, acc);

        float dx1 = p1.x - pd.x, dy1 = p1.y - pd.y, dz1 = p1.z - pd.z;
        float dist1 = sqrtf(fmaf(dx1, dx1, fmaf(dy1, dy1, dz1*dz1)));
        edge_contrib(sw1, hd, a1, dist1, acc);
    }
    if (k < dg) {
        int s0 = esrc[r0 + k];
        float4 a0 = xp4[2*s0], p0 = xp4[2*s0+1];
        float dx0 = p0.x - pd.x, dy0 = p0.y - pd.y, dz0 = p0.z - pd.z;
        float dist0 = sqrtf(fmaf(dx0, dx0, fmaf(dy0, dy0, dz0*dz0)));
        edge_contrib(sw1, hd, a0, dist0, acc);
    }

    // ---- Phase C: node MLP + softmax + pooling ----
    float c = (float)dg;
    float inv = fast_rcp(fmaxf(c, 1.0f));
    float h[16];
    #pragma unroll
    for (int j = 0; j < 16; ++j) h[j] = c * sb2[j];
    #pragma unroll
    for (int i = 0; i < 16; ++i) {
        float f = acc[i];
        #pragma unroll
        for (int j4 = 0; j4 < 4; ++j4) {
            float4 w = *(const float4*)&sw2[i*16 + 4*j4];
            h[4*j4+0] = fmaf(f, w.x, h[4*j4+0]);
            h[4*j4+1] = fmaf(f, w.y, h[4*j4+1]);
            h[4*j4+2] = fmaf(f, w.z, h[4*j4+2]);
            h[4*j4+3] = fmaf(f, w.w, h[4*j4+3]);
        }
    }
    #pragma unroll
    for (int j = 0; j < 16; ++j) h[j] = fmaxf(h[j] * inv, 0.0f);

    float l0 = spb[0], l1 = spb[1];
    #pragma unroll
    for (int j = 0; j < 16; ++j) {
        l0 = fmaf(h[j], spw[2*j+0], l0);
        l1 = fmaf(h[j], spw[2*j+1], l1);
    }
    float m = fmaxf(l0, l1);
    float e0 = __expf(l0 - m), e1 = __expf(l1 - m);
    float r = fast_rcp(e0 + e1);
    float s0 = e0 * r, s1 = e1 * r;
    s_out[2*n+0] = s0;
    s_out[2*n+1] = s1;

    float w[32];
    #pragma unroll
    for (int j = 0; j < 16; ++j) { w[j] = s0 * h[j]; w[16+j] = s1 * h[j]; }

    int b = batch[n];
    #pragma unroll
    for (int o = 1; o < 64; o <<= 1) {
        int bn = __shfl_down(b, o);
        bool take = (lane + o < 64) && (bn == b);
        #pragma unroll
        for (int cc = 0; cc < 32; ++cc) {
            float vn = __shfl_down(w[cc], o);
            if (take) w[cc] += vn;
        }
    }
    int bp = __shfl_up(b, 1);
    if (lane == 0 || bp != b) {
        float* pg = pooled + 32*b;
        #pragma unroll
        for (int cc = 0; cc < 32; ++cc) unsafeAtomicAdd(pg + cc, w[cc]);
    }
}

// ---------------------------------------------------------------------------
// K3: per-graph heads. z, recon, analytic potential + forces.
// ---------------------------------------------------------------------------
__global__ __launch_bounds__(256) void graph_kernel(
    const float* __restrict__ pooled,
    const float* __restrict__ toz_w, const float* __restrict__ toz_b,
    const float* __restrict__ vp_w1, const float* __restrict__ vp_b1,
    const float* __restrict__ vp_w2, const float* __restrict__ vp_b2,
    const float* __restrict__ bridge_w, const float* __restrict__ bridge_b,
    float* __restrict__ out_recon, float* __restrict__ out_z,
    float* __restrict__ out_forces, float* __restrict__ out_V)
{
    int g = blockIdx.x * 256 + threadIdx.x;
    if (g >= NUM_GRAPHS) return;

    const float* P = pooled + 32*g;
    float z[8];
    #pragma unroll
    for (int k = 0; k < 2; ++k) {
        #pragma unroll
        for (int d = 0; d < 4; ++d) {
            float a = toz_b[d];
            #pragma unroll
            for (int i = 0; i < 16; ++i) a = fmaf(P[16*k+i], toz_w[4*i+d], a);
            z[4*k+d] = a;
        }
    }
    #pragma unroll
    for (int i = 0; i < 8; ++i) out_z[8*g+i] = z[i];

    #pragma unroll
    for (int j = 0; j < 32; ++j) {
        float a = bridge_b[j];
        #pragma unroll
        for (int i = 0; i < 8; ++i) a = fmaf(z[i], bridge_w[32*i+j], a);
        out_recon[32*g+j] = a;
    }

    float d0 = z[0]-z[4], d1 = z[1]-z[5];
    float dd = sqrtf(d0*d0 + d1*d1 + 1e-6f);

    float V = vp_b2[0];
    float dV = 0.0f;
    #pragma unroll
    for (int j = 0; j < 32; ++j) {
        float w1 = vp_w1[j];
        float t  = fmaf(dd, w1, vp_b1[j]);
        float et = __expf(t);
        float sp = __logf(1.0f + et);
        float sg = et / (1.0f + et);
        float w2 = vp_w2[j];
        V  = fmaf(sp, w2, V);
        dV = fmaf(sg * w1, w2, dV);
    }
    out_V[g] = V;

    float scale = dV / dd;
    float gx = scale * d0, gy = scale * d1;
    out_forces[4*g+0] = -gx;
    out_forces[4*g+1] = -gy;
    out_forces[4*g+2] =  gx;
    out_forces[4*g+3] =  gy;
}

// ---------------------------------------------------------------------------
extern "C" void kernel_launch(void* const* d_in, const int* in_sizes, int n_in,
                              void* d_out, int out_size, void* d_ws, size_t ws_size,
                              hipStream_t stream) {
    const float* x        = (const float*)d_in[0];
    const float* pos      = (const float*)d_in[1];
    const int*   ei       = (const int*)  d_in[2];
    const int*   batch    = (const int*)  d_in[3];
    const float* enc_w1   = (const float*)d_in[4];
    const float* enc_b1   = (const float*)d_in[5];
    const float* enc_w2   = (const float*)d_in[6];
    const float* enc_b2   = (const float*)d_in[7];
    const float* pool_w   = (const float*)d_in[8];
    const float* pool_b   = (const float*)d_in[9];
    const float* toz_w    = (const float*)d_in[10];
    const float* toz_b    = (const float*)d_in[11];
    const float* vp_w1    = (const float*)d_in[12];
    const float* vp_b1    = (const float*)d_in[13];
    const float* vp_w2    = (const float*)d_in[14];
    const float* vp_b2    = (const float*)d_in[15];
    const float* bridge_w = (const float*)d_in[16];
    const float* bridge_b = (const float*)d_in[17];

    // workspace layout (4B units), ~26 MB
    int*   cursor = (int*)d_ws;                              // 256
    float* pooled = (float*)d_ws + NBKT;                     // 32768
    int*   staged = (int*)d_ws + NBKT + 32768;               // 256*17408
    float* xp     = (float*)(staged + (size_t)NBKT*CAPK);    // 2097152

    float* out        = (float*)d_out;
    float* out_recon  = out;                        // 1024*32
    float* out_z      = out_recon + 1024*32;        // 1024*8
    float* out_s      = out_z + 1024*8;             // 262144*2
    float* out_forces = out_s + (size_t)N_NODES*2;  // 1024*4
    float* out_V      = out_forces + 1024*4;        // 1024

    hipMemsetAsync(d_ws, 0, (size_t)(NBKT + 32768) * sizeof(float), stream);

    bin_pack_kernel<<<N_EDGES/EPB, 256, 0, stream>>>(ei, x, pos, cursor, staged, xp);
    fused_node_kernel<<<NBKT*4, 256, 0, stream>>>(
        xp, cursor, staged, batch,
        enc_w1, enc_b1, enc_w2, enc_b2, pool_w, pool_b, out_s, pooled);
    graph_kernel<<<NUM_GRAPHS/256, 256, 0, stream>>>(
        pooled, toz_w, toz_b, vp_w1, vp_b1, vp_w2, vp_b2,
        bridge_w, bridge_b, out_recon, out_z, out_forces, out_V);
}

// Round 11
// 250.641 us; speedup vs baseline: 1.3152x; 1.1504x over previous
//
#include <hip/hip_runtime.h>
#include <math.h>

#define N_NODES   262144
#define N_EDGES   4194304
#define NUM_GRAPHS 1024
#define NBKT      256          // buckets (dst >> 10), 1024 nodes each
#define BNODE     1024         // nodes per fused block (FULL bucket, no filter)
#define CAPK      17408        // bucket capacity (mean 16384, +8 sigma)
#define EPB       8192         // edges per binning block

static __device__ __forceinline__ float fast_rcp(float v) {
    return __builtin_amdgcn_rcpf(v);
}

// ---------------------------------------------------------------------------
// K1: one-pass binning into 256 buckets + node packing fused in.
// (r9 config, kept byte-identical: remainder dropped 160 -> 140us with it.)
// ---------------------------------------------------------------------------
__global__ __launch_bounds__(256) void bin_pack_kernel(
    const int* __restrict__ ei, const float* __restrict__ x,
    const float* __restrict__ pos,
    int* __restrict__ cursor, int* __restrict__ staged,
    float* __restrict__ xp)
{
    __shared__ int cnt[NBKT], rcnt[NBKT], lbase[NBKT], gbase[NBKT];
    __shared__ int stage[EPB];                 // 32 KB
    __shared__ int wsum[4];
    int tid = threadIdx.x;
    cnt[tid] = 0; rcnt[tid] = 0;
    __syncthreads();

    // ---- pack 512 nodes (2 per thread), independent of edge work ----
    {
        int n0 = blockIdx.x * 512 + tid;
        int n1 = n0 + 256;
        float4 xv0 = *(const float4*)(x + 4*n0);
        float4 xv1 = *(const float4*)(x + 4*n1);
        float4 pv0 = make_float4(pos[3*n0+0], pos[3*n0+1], pos[3*n0+2], 0.0f);
        float4 pv1 = make_float4(pos[3*n1+0], pos[3*n1+1], pos[3*n1+2], 0.0f);
        float4* o0 = (float4*)(xp + 8*n0);
        float4* o1 = (float4*)(xp + 8*n1);
        o0[0] = xv0; o0[1] = pv0;
        o1[0] = xv1; o1[1] = pv1;
    }

    // ---- histogram (dst kept in regs for the rank pass) ----
    int base = blockIdx.x * EPB;
    const int4* d4 = (const int4*)(ei + N_EDGES + base);
    const int4* s4 = (const int4*)(ei + base);
    int4 dv[8];
    #pragma unroll
    for (int i = 0; i < 8; ++i) {
        dv[i] = d4[i*256 + tid];
        atomicAdd(&cnt[dv[i].x >> 10], 1);
        atomicAdd(&cnt[dv[i].y >> 10], 1);
        atomicAdd(&cnt[dv[i].z >> 10], 1);
        atomicAdd(&cnt[dv[i].w >> 10], 1);
    }
    __syncthreads();

    // ---- local exclusive scan (1 bin/thread) + global cursor alloc ----
    int c = cnt[tid];
    int lane = tid & 63, wid = tid >> 6;
    int inc = c;
    #pragma unroll
    for (int o = 1; o < 64; o <<= 1) {
        int t = __shfl_up(inc, o);
        if (lane >= o) inc += t;
    }
    if (lane == 63) wsum[wid] = inc;
    __syncthreads();
    int wb = 0;
    #pragma unroll
    for (int w = 0; w < 4; ++w) if (w < wid) wb += wsum[w];
    lbase[tid] = wb + inc - c;
    gbase[tid] = c ? atomicAdd(cursor + tid, c) : 0;
    __syncthreads();

    // ---- rank + stage: ((dst&1023)<<18) | src ----
    #pragma unroll
    for (int i = 0; i < 8; ++i) {
        int4 sv = s4[i*256 + tid];
        int d, s, bk, r;
        d = dv[i].x; s = sv.x; bk = d >> 10; r = atomicAdd(&rcnt[bk], 1);
        stage[lbase[bk] + r] = ((d & 1023) << 18) | s;
        d = dv[i].y; s = sv.y; bk = d >> 10; r = atomicAdd(&rcnt[bk], 1);
        stage[lbase[bk] + r] = ((d & 1023) << 18) | s;
        d = dv[i].z; s = sv.z; bk = d >> 10; r = atomicAdd(&rcnt[bk], 1);
        stage[lbase[bk] + r] = ((d & 1023) << 18) | s;
        d = dv[i].w; s = sv.w; bk = d >> 10; r = atomicAdd(&rcnt[bk], 1);
        stage[lbase[bk] + r] = ((d & 1023) << 18) | s;
    }
    __syncthreads();

    // ---- write-out: 32 lanes per bin, ~128B contiguous segments ----
    int sub = tid & 31;
    int grp = tid >> 5;                        // 8 groups of 32 lanes
    #pragma unroll
    for (int pass = 0; pass < NBKT/8; ++pass) {
        int bk  = pass*8 + grp;
        int c2  = rcnt[bk];
        int lb  = lbase[bk];
        int gb  = gbase[bk];
        int lim = CAPK - gb; if (c2 > lim) c2 = lim;   // ~8-sigma guard
        for (int k = sub; k < c2; k += 32)
            staged[bk*CAPK + gb + k] = stage[lb + k];
    }
}

// ---------------------------------------------------------------------------
// Per-edge contribution: rows 4..7 (x[src]) + row 8 (dist) of enc_w1, on top
// of the per-node precomputed hd[] (bias + dst rows). silu accumulate.
// ---------------------------------------------------------------------------
static __device__ __forceinline__ void edge_contrib(
    const float* __restrict__ sw1, const float* __restrict__ hd,
    float4 xs, float dist, float* __restrict__ acc)
{
    float h[16];
    #pragma unroll
    for (int j4 = 0; j4 < 4; ++j4) {
        float4 w = *(const float4*)&sw1[4*16 + 4*j4];
        h[4*j4+0] = fmaf(xs.x, w.x, hd[4*j4+0]);
        h[4*j4+1] = fmaf(xs.x, w.y, hd[4*j4+1]);
        h[4*j4+2] = fmaf(xs.x, w.z, hd[4*j4+2]);
        h[4*j4+3] = fmaf(xs.x, w.w, hd[4*j4+3]);
    }
    #pragma unroll
    for (int j4 = 0; j4 < 4; ++j4) {
        float4 w = *(const float4*)&sw1[5*16 + 4*j4];
        h[4*j4+0] = fmaf(xs.y, w.x, h[4*j4+0]);
        h[4*j4+1] = fmaf(xs.y, w.y, h[4*j4+1]);
        h[4*j4+2] = fmaf(xs.y, w.z, h[4*j4+2]);
        h[4*j4+3] = fmaf(xs.y, w.w, h[4*j4+3]);
    }
    #pragma unroll
    for (int j4 = 0; j4 < 4; ++j4) {
        float4 w = *(const float4*)&sw1[6*16 + 4*j4];
        h[4*j4+0] = fmaf(xs.z, w.x, h[4*j4+0]);
        h[4*j4+1] = fmaf(xs.z, w.y, h[4*j4+1]);
        h[4*j4+2] = fmaf(xs.z, w.z, h[4*j4+2]);
        h[4*j4+3] = fmaf(xs.z, w.w, h[4*j4+3]);
    }
    #pragma unroll
    for (int j4 = 0; j4 < 4; ++j4) {
        float4 w = *(const float4*)&sw1[7*16 + 4*j4];
        h[4*j4+0] = fmaf(xs.w, w.x, h[4*j4+0]);
        h[4*j4+1] = fmaf(xs.w, w.y, h[4*j4+1]);
        h[4*j4+2] = fmaf(xs.w, w.z, h[4*j4+2]);
        h[4*j4+3] = fmaf(xs.w, w.w, h[4*j4+3]);
    }
    #pragma unroll
    for (int j4 = 0; j4 < 4; ++j4) {
        float4 w = *(const float4*)&sw1[8*16 + 4*j4];
        h[4*j4+0] = fmaf(dist, w.x, h[4*j4+0]);
        h[4*j4+1] = fmaf(dist, w.y, h[4*j4+1]);
        h[4*j4+2] = fmaf(dist, w.z, h[4*j4+2]);
        h[4*j4+3] = fmaf(dist, w.w, h[4*j4+3]);
    }
    #pragma unroll
    for (int j = 0; j < 16; ++j) {
        float sg = fast_rcp(1.0f + __expf(-h[j]));
        acc[j] = fmaf(h[j], sg, acc[j]);
    }
}

// ---------------------------------------------------------------------------
// K2 (fused): one 1024-thread block per FULL 1024-node bucket (256 blocks).
// No node filtering -> staged read exactly 2x (hist + scatter), like the
// 112us configs (r9's quarter-filter read 8x: +55MB FETCH, +36us).
// Occupancy is work-limited at 16 waves/CU regardless of partitioning
// (262144 nodes = 4096 waves total), so the only partition criterion is
// read amplification. LDS ~75.7KB; ldeg reused as scatter cursor (dg,r0
// live in registers). Phase B/C per-thread code identical to r7 (2-wide,
// 64 VGPR; 4-wide spills at this budget per r8).
// ---------------------------------------------------------------------------
__global__ __launch_bounds__(1024, 4) void fused_node_kernel(
    const float* __restrict__ xp,
    const int* __restrict__ cursor, const int* __restrict__ staged,
    const int* __restrict__ batch,
    const float* __restrict__ w1, const float* __restrict__ b1,
    const float* __restrict__ w2, const float* __restrict__ b2,
    const float* __restrict__ pw, const float* __restrict__ pb,
    float* __restrict__ s_out, float* __restrict__ pooled)
{
    __shared__ int esrc[CAPK];                 // 69632 B
    __shared__ int ldeg[BNODE];                // 4096 B (hist, then cursor)
    __shared__ int wsum[16];
    __shared__ __align__(16) float sw1[144];
    __shared__ float sb1[16];
    __shared__ __align__(16) float sw2[256];
    __shared__ float sb2[16];
    __shared__ float spw[32];
    __shared__ float spb[2];

    int tid = threadIdx.x;
    if (tid < 144) sw1[tid] = w1[tid];
    if (tid >= 144 && tid < 160) sb1[tid - 144] = b1[tid - 144];
    if (tid >= 160 && tid < 176) sb2[tid - 160] = b2[tid - 160];
    if (tid >= 176 && tid < 208) spw[tid - 176] = pw[tid - 176];
    if (tid >= 208 && tid < 210) spb[tid - 208] = pb[tid - 208];
    if (tid >= 256 && tid < 512) sw2[tid - 256] = w2[tid - 256];
    ldeg[tid] = 0;
    __syncthreads();

    int bkt  = blockIdx.x;
    int cnt  = cursor[bkt]; if (cnt > CAPK) cnt = CAPK;
    int base = bkt * CAPK;
    int nb0  = bkt * BNODE;

    // ---- Phase A: counting sort into LDS (full bucket, no filter) ----
    for (int i = tid; i < cnt; i += 1024)
        atomicAdd(&ldeg[staged[base + i] >> 18], 1);
    __syncthreads();

    int dg   = ldeg[tid];                      // degree of node nb0+tid
    int lane = tid & 63, wid = tid >> 6;       // wid 0..15
    int inc  = dg;
    #pragma unroll
    for (int o = 1; o < 64; o <<= 1) {
        int t = __shfl_up(inc, o);
        if (lane >= o) inc += t;
    }
    if (lane == 63) wsum[wid] = inc;
    __syncthreads();
    int wb = 0;
    #pragma unroll
    for (int w = 0; w < 16; ++w) if (w < wid) wb += wsum[w];
    int r0 = wb + inc - dg;                    // exclusive row offset in esrc
    ldeg[tid] = r0;                            // reuse as scatter cursor
    __syncthreads();

    for (int i = tid; i < cnt; i += 1024) {
        int p  = staged[base + i];             // L2/L3-hot re-read
        int lo = p >> 18;
        int r  = atomicAdd(&ldeg[lo], 1);
        esrc[r] = p & 0x3FFFF;
    }
    __syncthreads();

    // ---- Phase B: per-node gather + edge MLP (r7 verbatim) ----
    int n = nb0 + tid;
    const float4* xp4 = (const float4*)xp;
    float4 xd = xp4[2*n];
    float4 pd = xp4[2*n+1];

    // hd[j] = b1[j] + sum_{i<4} xd_i * w1[i][j]  -- hoisted out of edge loop
    float hd[16];
    #pragma unroll
    for (int j = 0; j < 16; ++j) hd[j] = sb1[j];
    #pragma unroll
    for (int j4 = 0; j4 < 4; ++j4) {
        float4 w0 = *(const float4*)&sw1[0*16 + 4*j4];
        float4 w1r = *(const float4*)&sw1[1*16 + 4*j4];
        float4 w2r = *(const float4*)&sw1[2*16 + 4*j4];
        float4 w3r = *(const float4*)&sw1[3*16 + 4*j4];
        hd[4*j4+0] = fmaf(xd.x, w0.x, hd[4*j4+0]);
        hd[4*j4+1] = fmaf(xd.x, w0.y, hd[4*j4+1]);
        hd[4*j4+2] = fmaf(xd.x, w0.z, hd[4*j4+2]);
        hd[4*j4+3] = fmaf(xd.x, w0.w, hd[4*j4+3]);
        hd[4*j4+0] = fmaf(xd.y, w1r.x, hd[4*j4+0]);
        hd[4*j4+1] = fmaf(xd.y, w1r.y, hd[4*j4+1]);
        hd[4*j4+2] = fmaf(xd.y, w1r.z, hd[4*j4+2]);
        hd[4*j4+3] = fmaf(xd.y, w1r.w, hd[4*j4+3]);
        hd[4*j4+0] = fmaf(xd.z, w2r.x, hd[4*j4+0]);
        hd[4*j4+1] = fmaf(xd.z, w2r.y, hd[4*j4+1]);
        hd[4*j4+2] = fmaf(xd.z, w2r.z, hd[4*j4+2]);
        hd[4*j4+3] = fmaf(xd.z, w2r.w, hd[4*j4+3]);
        hd[4*j4+0] = fmaf(xd.w, w3r.x, hd[4*j4+0]);
        hd[4*j4+1] = fmaf(xd.w, w3r.y, hd[4*j4+1]);
        hd[4*j4+2] = fmaf(xd.w, w3r.z, hd[4*j4+2]);
        hd[4*j4+3] = fmaf(xd.w, w3r.w, hd[4*j4+3]);
    }

    float acc[16];
    #pragma unroll
    for (int j = 0; j < 16; ++j) acc[j] = 0.0f;

    int k = 0;
    for (; k + 2 <= dg; k += 2) {
        int s0 = esrc[r0 + k];
        int s1 = esrc[r0 + k + 1];
        float4 a0 = xp4[2*s0], p0 = xp4[2*s0+1];
        float4 a1 = xp4[2*s1], p1 = xp4[2*s1+1];

        float dx0 = p0.x - pd.x, dy0 = p0.y - pd.y, dz0 = p0.z - pd.z;
        float dist0 = sqrtf(fmaf(dx0, dx0, fmaf(dy0, dy0, dz0*dz0)));
        edge_contrib(sw1, hd, a0, dist0, acc);

        float dx1 = p1.x - pd.x, dy1 = p1.y - pd.y, dz1 = p1.z - pd.z;
        float dist1 = sqrtf(fmaf(dx1, dx1, fmaf(dy1, dy1, dz1*dz1)));
        edge_contrib(sw1, hd, a1, dist1, acc);
    }
    if (k < dg) {
        int s0 = esrc[r0 + k];
        float4 a0 = xp4[2*s0], p0 = xp4[2*s0+1];
        float dx0 = p0.x - pd.x, dy0 = p0.y - pd.y, dz0 = p0.z - pd.z;
        float dist0 = sqrtf(fmaf(dx0, dx0, fmaf(dy0, dy0, dz0*dz0)));
        edge_contrib(sw1, hd, a0, dist0, acc);
    }

    // ---- Phase C: node MLP + softmax + pooling ----
    float c = (float)dg;
    float inv = fast_rcp(fmaxf(c, 1.0f));
    float h[16];
    #pragma unroll
    for (int j = 0; j < 16; ++j) h[j] = c * sb2[j];
    #pragma unroll
    for (int i = 0; i < 16; ++i) {
        float f = acc[i];
        #pragma unroll
        for (int j4 = 0; j4 < 4; ++j4) {
            float4 w = *(const float4*)&sw2[i*16 + 4*j4];
            h[4*j4+0] = fmaf(f, w.x, h[4*j4+0]);
            h[4*j4+1] = fmaf(f, w.y, h[4*j4+1]);
            h[4*j4+2] = fmaf(f, w.z, h[4*j4+2]);
            h[4*j4+3] = fmaf(f, w.w, h[4*j4+3]);
        }
    }
    #pragma unroll
    for (int j = 0; j < 16; ++j) h[j] = fmaxf(h[j] * inv, 0.0f);

    float l0 = spb[0], l1 = spb[1];
    #pragma unroll
    for (int j = 0; j < 16; ++j) {
        l0 = fmaf(h[j], spw[2*j+0], l0);
        l1 = fmaf(h[j], spw[2*j+1], l1);
    }
    float m = fmaxf(l0, l1);
    float e0 = __expf(l0 - m), e1 = __expf(l1 - m);
    float r = fast_rcp(e0 + e1);
    float s0 = e0 * r, s1 = e1 * r;
    s_out[2*n+0] = s0;
    s_out[2*n+1] = s1;

    float w[32];
    #pragma unroll
    for (int j = 0; j < 16; ++j) { w[j] = s0 * h[j]; w[16+j] = s1 * h[j]; }

    int b = batch[n];
    #pragma unroll
    for (int o = 1; o < 64; o <<= 1) {
        int bn = __shfl_down(b, o);
        bool take = (lane + o < 64) && (bn == b);
        #pragma unroll
        for (int cc = 0; cc < 32; ++cc) {
            float vn = __shfl_down(w[cc], o);
            if (take) w[cc] += vn;
        }
    }
    int bp = __shfl_up(b, 1);
    if (lane == 0 || bp != b) {
        float* pg = pooled + 32*b;
        #pragma unroll
        for (int cc = 0; cc < 32; ++cc) unsafeAtomicAdd(pg + cc, w[cc]);
    }
}

// ---------------------------------------------------------------------------
// K3: per-graph heads. z, recon, analytic potential + forces.
// ---------------------------------------------------------------------------
__global__ __launch_bounds__(256) void graph_kernel(
    const float* __restrict__ pooled,
    const float* __restrict__ toz_w, const float* __restrict__ toz_b,
    const float* __restrict__ vp_w1, const float* __restrict__ vp_b1,
    const float* __restrict__ vp_w2, const float* __restrict__ vp_b2,
    const float* __restrict__ bridge_w, const float* __restrict__ bridge_b,
    float* __restrict__ out_recon, float* __restrict__ out_z,
    float* __restrict__ out_forces, float* __restrict__ out_V)
{
    int g = blockIdx.x * 256 + threadIdx.x;
    if (g >= NUM_GRAPHS) return;

    const float* P = pooled + 32*g;
    float z[8];
    #pragma unroll
    for (int k = 0; k < 2; ++k) {
        #pragma unroll
        for (int d = 0; d < 4; ++d) {
            float a = toz_b[d];
            #pragma unroll
            for (int i = 0; i < 16; ++i) a = fmaf(P[16*k+i], toz_w[4*i+d], a);
            z[4*k+d] = a;
        }
    }
    #pragma unroll
    for (int i = 0; i < 8; ++i) out_z[8*g+i] = z[i];

    #pragma unroll
    for (int j = 0; j < 32; ++j) {
        float a = bridge_b[j];
        #pragma unroll
        for (int i = 0; i < 8; ++i) a = fmaf(z[i], bridge_w[32*i+j], a);
        out_recon[32*g+j] = a;
    }

    float d0 = z[0]-z[4], d1 = z[1]-z[5];
    float dd = sqrtf(d0*d0 + d1*d1 + 1e-6f);

    float V = vp_b2[0];
    float dV = 0.0f;
    #pragma unroll
    for (int j = 0; j < 32; ++j) {
        float w1 = vp_w1[j];
        float t  = fmaf(dd, w1, vp_b1[j]);
        float et = __expf(t);
        float sp = __logf(1.0f + et);
        float sg = et / (1.0f + et);
        float w2 = vp_w2[j];
        V  = fmaf(sp, w2, V);
        dV = fmaf(sg * w1, w2, dV);
    }
    out_V[g] = V;

    float scale = dV / dd;
    float gx = scale * d0, gy = scale * d1;
    out_forces[4*g+0] = -gx;
    out_forces[4*g+1] = -gy;
    out_forces[4*g+2] =  gx;
    out_forces[4*g+3] =  gy;
}

// ---------------------------------------------------------------------------
extern "C" void kernel_launch(void* const* d_in, const int* in_sizes, int n_in,
                              void* d_out, int out_size, void* d_ws, size_t ws_size,
                              hipStream_t stream) {
    const float* x        = (const float*)d_in[0];
    const float* pos      = (const float*)d_in[1];
    const int*   ei       = (const int*)  d_in[2];
    const int*   batch    = (const int*)  d_in[3];
    const float* enc_w1   = (const float*)d_in[4];
    const float* enc_b1   = (const float*)d_in[5];
    const float* enc_w2   = (const float*)d_in[6];
    const float* enc_b2   = (const float*)d_in[7];
    const float* pool_w   = (const float*)d_in[8];
    const float* pool_b   = (const float*)d_in[9];
    const float* toz_w    = (const float*)d_in[10];
    const float* toz_b    = (const float*)d_in[11];
    const float* vp_w1    = (const float*)d_in[12];
    const float* vp_b1    = (const float*)d_in[13];
    const float* vp_w2    = (const float*)d_in[14];
    const float* vp_b2    = (const float*)d_in[15];
    const float* bridge_w = (const float*)d_in[16];
    const float* bridge_b = (const float*)d_in[17];

    // workspace layout (4B units), ~26 MB
    int*   cursor = (int*)d_ws;                              // 256
    float* pooled = (float*)d_ws + NBKT;                     // 32768
    int*   staged = (int*)d_ws + NBKT + 32768;               // 256*17408
    float* xp     = (float*)(staged + (size_t)NBKT*CAPK);    // 2097152

    float* out        = (float*)d_out;
    float* out_recon  = out;                        // 1024*32
    float* out_z      = out_recon + 1024*32;        // 1024*8
    float* out_s      = out_z + 1024*8;             // 262144*2
    float* out_forces = out_s + (size_t)N_NODES*2;  // 1024*4
    float* out_V      = out_forces + 1024*4;        // 1024

    hipMemsetAsync(d_ws, 0, (size_t)(NBKT + 32768) * sizeof(float), stream);

    bin_pack_kernel<<<N_EDGES/EPB, 256, 0, stream>>>(ei, x, pos, cursor, staged, xp);
    fused_node_kernel<<<NBKT, 1024, 0, stream>>>(
        xp, cursor, staged, batch,
        enc_w1, enc_b1, enc_w2, enc_b2, pool_w, pool_b, out_s, pooled);
    graph_kernel<<<NUM_GRAPHS/256, 256, 0, stream>>>(
        pooled, toz_w, toz_b, vp_w1, vp_b1, vp_w2, vp_b2,
        bridge_w, bridge_b, out_recon, out_z, out_forces, out_V);
}

// Round 12
// 216.842 us; speedup vs baseline: 1.5202x; 1.1559x over previous
//
#include <hip/hip_runtime.h>
#include <math.h>

#define N_NODES   262144
#define N_EDGES   4194304
#define NUM_GRAPHS 1024
#define NBKT      256          // buckets (dst >> 10), 1024 nodes each
#define BNODE     1024         // nodes per fused block (FULL bucket, no filter)
#define CAPK      17408        // bucket capacity (mean 16384, +8 sigma)
#define EPB       8192         // edges per binning block
#define CSTRIDE   32           // cursor padding: 1 cursor per 128B line

typedef _Float16 h8 __attribute__((ext_vector_type(8)));

static __device__ __forceinline__ float fast_rcp(float v) {
    return __builtin_amdgcn_rcpf(v);
}

// ---------------------------------------------------------------------------
// K1: one-pass binning into 256 buckets + fp16 node packing fused in.
// xp record: half x[4], pos[3], pad = 16B/node -> xp total 4MB = one XCD-L2,
// so fused's random gathers become L2 hits instead of L3/HBM misses.
// Cursors padded to 1/128B-line: 131K global atomics previously hit 8 lines
// (256 packed ints) -> L2 same-line RMW serialization; now bank-parallel.
// ---------------------------------------------------------------------------
__global__ __launch_bounds__(256) void bin_pack_kernel(
    const int* __restrict__ ei, const float* __restrict__ x,
    const float* __restrict__ pos,
    int* __restrict__ cursor, int* __restrict__ staged,
    h8* __restrict__ xp)
{
    __shared__ int cnt[NBKT], rcnt[NBKT], lbase[NBKT], gbase[NBKT];
    __shared__ int stage[EPB];                 // 32 KB
    __shared__ int wsum[4];
    int tid = threadIdx.x;
    cnt[tid] = 0; rcnt[tid] = 0;
    __syncthreads();

    // ---- pack 512 nodes (2 per thread) as fp16 records ----
    {
        int n0 = blockIdx.x * 512 + tid;
        int n1 = n0 + 256;
        float4 xv0 = *(const float4*)(x + 4*n0);
        float4 xv1 = *(const float4*)(x + 4*n1);
        h8 o0, o1;
        o0[0] = (_Float16)xv0.x; o0[1] = (_Float16)xv0.y;
        o0[2] = (_Float16)xv0.z; o0[3] = (_Float16)xv0.w;
        o0[4] = (_Float16)pos[3*n0+0]; o0[5] = (_Float16)pos[3*n0+1];
        o0[6] = (_Float16)pos[3*n0+2]; o0[7] = (_Float16)0.0f;
        o1[0] = (_Float16)xv1.x; o1[1] = (_Float16)xv1.y;
        o1[2] = (_Float16)xv1.z; o1[3] = (_Float16)xv1.w;
        o1[4] = (_Float16)pos[3*n1+0]; o1[5] = (_Float16)pos[3*n1+1];
        o1[6] = (_Float16)pos[3*n1+2]; o1[7] = (_Float16)0.0f;
        xp[n0] = o0;
        xp[n1] = o1;
    }

    // ---- histogram (dst kept in regs for the rank pass) ----
    int base = blockIdx.x * EPB;
    const int4* d4 = (const int4*)(ei + N_EDGES + base);
    const int4* s4 = (const int4*)(ei + base);
    int4 dv[8];
    #pragma unroll
    for (int i = 0; i < 8; ++i) {
        dv[i] = d4[i*256 + tid];
        atomicAdd(&cnt[dv[i].x >> 10], 1);
        atomicAdd(&cnt[dv[i].y >> 10], 1);
        atomicAdd(&cnt[dv[i].z >> 10], 1);
        atomicAdd(&cnt[dv[i].w >> 10], 1);
    }
    __syncthreads();

    // ---- local exclusive scan (1 bin/thread) + global cursor alloc ----
    int c = cnt[tid];
    int lane = tid & 63, wid = tid >> 6;
    int inc = c;
    #pragma unroll
    for (int o = 1; o < 64; o <<= 1) {
        int t = __shfl_up(inc, o);
        if (lane >= o) inc += t;
    }
    if (lane == 63) wsum[wid] = inc;
    __syncthreads();
    int wb = 0;
    #pragma unroll
    for (int w = 0; w < 4; ++w) if (w < wid) wb += wsum[w];
    lbase[tid] = wb + inc - c;
    gbase[tid] = c ? atomicAdd(cursor + tid*CSTRIDE, c) : 0;
    __syncthreads();

    // ---- rank + stage: ((dst&1023)<<18) | src ----
    #pragma unroll
    for (int i = 0; i < 8; ++i) {
        int4 sv = s4[i*256 + tid];
        int d, s, bk, r;
        d = dv[i].x; s = sv.x; bk = d >> 10; r = atomicAdd(&rcnt[bk], 1);
        stage[lbase[bk] + r] = ((d & 1023) << 18) | s;
        d = dv[i].y; s = sv.y; bk = d >> 10; r = atomicAdd(&rcnt[bk], 1);
        stage[lbase[bk] + r] = ((d & 1023) << 18) | s;
        d = dv[i].z; s = sv.z; bk = d >> 10; r = atomicAdd(&rcnt[bk], 1);
        stage[lbase[bk] + r] = ((d & 1023) << 18) | s;
        d = dv[i].w; s = sv.w; bk = d >> 10; r = atomicAdd(&rcnt[bk], 1);
        stage[lbase[bk] + r] = ((d & 1023) << 18) | s;
    }
    __syncthreads();

    // ---- write-out: 32 lanes per bin, ~128B contiguous segments ----
    int sub = tid & 31;
    int grp = tid >> 5;                        // 8 groups of 32 lanes
    #pragma unroll
    for (int pass = 0; pass < NBKT/8; ++pass) {
        int bk  = pass*8 + grp;
        int c2  = rcnt[bk];
        int lb  = lbase[bk];
        int gb  = gbase[bk];
        int lim = CAPK - gb; if (c2 > lim) c2 = lim;   // ~8-sigma guard
        for (int k = sub; k < c2; k += 32)
            staged[bk*CAPK + gb + k] = stage[lb + k];
    }
}

// ---------------------------------------------------------------------------
// Per-edge contribution: rows 4..7 (x[src]) + row 8 (dist) of enc_w1, on top
// of the per-node precomputed hd[] (bias + dst rows). silu accumulate.
// ---------------------------------------------------------------------------
static __device__ __forceinline__ void edge_contrib(
    const float* __restrict__ sw1, const float* __restrict__ hd,
    float4 xs, float dist, float* __restrict__ acc)
{
    float h[16];
    #pragma unroll
    for (int j4 = 0; j4 < 4; ++j4) {
        float4 w = *(const float4*)&sw1[4*16 + 4*j4];
        h[4*j4+0] = fmaf(xs.x, w.x, hd[4*j4+0]);
        h[4*j4+1] = fmaf(xs.x, w.y, hd[4*j4+1]);
        h[4*j4+2] = fmaf(xs.x, w.z, hd[4*j4+2]);
        h[4*j4+3] = fmaf(xs.x, w.w, hd[4*j4+3]);
    }
    #pragma unroll
    for (int j4 = 0; j4 < 4; ++j4) {
        float4 w = *(const float4*)&sw1[5*16 + 4*j4];
        h[4*j4+0] = fmaf(xs.y, w.x, h[4*j4+0]);
        h[4*j4+1] = fmaf(xs.y, w.y, h[4*j4+1]);
        h[4*j4+2] = fmaf(xs.y, w.z, h[4*j4+2]);
        h[4*j4+3] = fmaf(xs.y, w.w, h[4*j4+3]);
    }
    #pragma unroll
    for (int j4 = 0; j4 < 4; ++j4) {
        float4 w = *(const float4*)&sw1[6*16 + 4*j4];
        h[4*j4+0] = fmaf(xs.z, w.x, h[4*j4+0]);
        h[4*j4+1] = fmaf(xs.z, w.y, h[4*j4+1]);
        h[4*j4+2] = fmaf(xs.z, w.z, h[4*j4+2]);
        h[4*j4+3] = fmaf(xs.z, w.w, h[4*j4+3]);
    }
    #pragma unroll
    for (int j4 = 0; j4 < 4; ++j4) {
        float4 w = *(const float4*)&sw1[7*16 + 4*j4];
        h[4*j4+0] = fmaf(xs.w, w.x, h[4*j4+0]);
        h[4*j4+1] = fmaf(xs.w, w.y, h[4*j4+1]);
        h[4*j4+2] = fmaf(xs.w, w.z, h[4*j4+2]);
        h[4*j4+3] = fmaf(xs.w, w.w, h[4*j4+3]);
    }
    #pragma unroll
    for (int j4 = 0; j4 < 4; ++j4) {
        float4 w = *(const float4*)&sw1[8*16 + 4*j4];
        h[4*j4+0] = fmaf(dist, w.x, h[4*j4+0]);
        h[4*j4+1] = fmaf(dist, w.y, h[4*j4+1]);
        h[4*j4+2] = fmaf(dist, w.z, h[4*j4+2]);
        h[4*j4+3] = fmaf(dist, w.w, h[4*j4+3]);
    }
    #pragma unroll
    for (int j = 0; j < 16; ++j) {
        float sg = fast_rcp(1.0f + __expf(-h[j]));
        acc[j] = fmaf(h[j], sg, acc[j]);
    }
}

// ---------------------------------------------------------------------------
// K2 (fused): r11 structure (full 1024-node bucket per 1024-thread block,
// staged read exactly 2x), with fp16 16B records: ONE 16B load per edge,
// 4MB total footprint = L2-resident. Compute stays fp32 post-convert.
// ---------------------------------------------------------------------------
__global__ __launch_bounds__(1024, 4) void fused_node_kernel(
    const h8* __restrict__ xp,
    const int* __restrict__ cursor, const int* __restrict__ staged,
    const int* __restrict__ batch,
    const float* __restrict__ w1, const float* __restrict__ b1,
    const float* __restrict__ w2, const float* __restrict__ b2,
    const float* __restrict__ pw, const float* __restrict__ pb,
    float* __restrict__ s_out, float* __restrict__ pooled)
{
    __shared__ int esrc[CAPK];                 // 69632 B
    __shared__ int ldeg[BNODE];                // 4096 B (hist, then cursor)
    __shared__ int wsum[16];
    __shared__ __align__(16) float sw1[144];
    __shared__ float sb1[16];
    __shared__ __align__(16) float sw2[256];
    __shared__ float sb2[16];
    __shared__ float spw[32];
    __shared__ float spb[2];

    int tid = threadIdx.x;
    if (tid < 144) sw1[tid] = w1[tid];
    if (tid >= 144 && tid < 160) sb1[tid - 144] = b1[tid - 144];
    if (tid >= 160 && tid < 176) sb2[tid - 160] = b2[tid - 160];
    if (tid >= 176 && tid < 208) spw[tid - 176] = pw[tid - 176];
    if (tid >= 208 && tid < 210) spb[tid - 208] = pb[tid - 208];
    if (tid >= 256 && tid < 512) sw2[tid - 256] = w2[tid - 256];
    ldeg[tid] = 0;
    __syncthreads();

    int bkt  = blockIdx.x;
    int cnt  = cursor[bkt*CSTRIDE]; if (cnt > CAPK) cnt = CAPK;
    int base = bkt * CAPK;
    int nb0  = bkt * BNODE;

    // ---- Phase A: counting sort into LDS (full bucket, no filter) ----
    for (int i = tid; i < cnt; i += 1024)
        atomicAdd(&ldeg[staged[base + i] >> 18], 1);
    __syncthreads();

    int dg   = ldeg[tid];                      // degree of node nb0+tid
    int lane = tid & 63, wid = tid >> 6;       // wid 0..15
    int inc  = dg;
    #pragma unroll
    for (int o = 1; o < 64; o <<= 1) {
        int t = __shfl_up(inc, o);
        if (lane >= o) inc += t;
    }
    if (lane == 63) wsum[wid] = inc;
    __syncthreads();
    int wb = 0;
    #pragma unroll
    for (int w = 0; w < 16; ++w) if (w < wid) wb += wsum[w];
    int r0 = wb + inc - dg;                    // exclusive row offset in esrc
    ldeg[tid] = r0;                            // reuse as scatter cursor
    __syncthreads();

    for (int i = tid; i < cnt; i += 1024) {
        int p  = staged[base + i];             // L2/L3-hot re-read
        int lo = p >> 18;
        int r  = atomicAdd(&ldeg[lo], 1);
        esrc[r] = p & 0x3FFFF;
    }
    __syncthreads();

    // ---- Phase B: per-node gather + edge MLP ----
    int n = nb0 + tid;
    h8 rd = xp[n];
    float4 xd = make_float4((float)rd[0], (float)rd[1], (float)rd[2], (float)rd[3]);
    float pdx = (float)rd[4], pdy = (float)rd[5], pdz = (float)rd[6];

    // hd[j] = b1[j] + sum_{i<4} xd_i * w1[i][j]  -- hoisted out of edge loop
    float hd[16];
    #pragma unroll
    for (int j = 0; j < 16; ++j) hd[j] = sb1[j];
    #pragma unroll
    for (int j4 = 0; j4 < 4; ++j4) {
        float4 w0 = *(const float4*)&sw1[0*16 + 4*j4];
        float4 w1r = *(const float4*)&sw1[1*16 + 4*j4];
        float4 w2r = *(const float4*)&sw1[2*16 + 4*j4];
        float4 w3r = *(const float4*)&sw1[3*16 + 4*j4];
        hd[4*j4+0] = fmaf(xd.x, w0.x, hd[4*j4+0]);
        hd[4*j4+1] = fmaf(xd.x, w0.y, hd[4*j4+1]);
        hd[4*j4+2] = fmaf(xd.x, w0.z, hd[4*j4+2]);
        hd[4*j4+3] = fmaf(xd.x, w0.w, hd[4*j4+3]);
        hd[4*j4+0] = fmaf(xd.y, w1r.x, hd[4*j4+0]);
        hd[4*j4+1] = fmaf(xd.y, w1r.y, hd[4*j4+1]);
        hd[4*j4+2] = fmaf(xd.y, w1r.z, hd[4*j4+2]);
        hd[4*j4+3] = fmaf(xd.y, w1r.w, hd[4*j4+3]);
        hd[4*j4+0] = fmaf(xd.z, w2r.x, hd[4*j4+0]);
        hd[4*j4+1] = fmaf(xd.z, w2r.y, hd[4*j4+1]);
        hd[4*j4+2] = fmaf(xd.z, w2r.z, hd[4*j4+2]);
        hd[4*j4+3] = fmaf(xd.z, w2r.w, hd[4*j4+3]);
        hd[4*j4+0] = fmaf(xd.w, w3r.x, hd[4*j4+0]);
        hd[4*j4+1] = fmaf(xd.w, w3r.y, hd[4*j4+1]);
        hd[4*j4+2] = fmaf(xd.w, w3r.z, hd[4*j4+2]);
        hd[4*j4+3] = fmaf(xd.w, w3r.w, hd[4*j4+3]);
    }

    float acc[16];
    #pragma unroll
    for (int j = 0; j < 16; ++j) acc[j] = 0.0f;

    int k = 0;
    for (; k + 2 <= dg; k += 2) {
        int s0 = esrc[r0 + k];
        int s1 = esrc[r0 + k + 1];
        h8 e0 = xp[s0];
        h8 e1 = xp[s1];

        float4 a0 = make_float4((float)e0[0], (float)e0[1], (float)e0[2], (float)e0[3]);
        float dx0 = (float)e0[4] - pdx, dy0 = (float)e0[5] - pdy, dz0 = (float)e0[6] - pdz;
        float dist0 = sqrtf(fmaf(dx0, dx0, fmaf(dy0, dy0, dz0*dz0)));
        edge_contrib(sw1, hd, a0, dist0, acc);

        float4 a1 = make_float4((float)e1[0], (float)e1[1], (float)e1[2], (float)e1[3]);
        float dx1 = (float)e1[4] - pdx, dy1 = (float)e1[5] - pdy, dz1 = (float)e1[6] - pdz;
        float dist1 = sqrtf(fmaf(dx1, dx1, fmaf(dy1, dy1, dz1*dz1)));
        edge_contrib(sw1, hd, a1, dist1, acc);
    }
    if (k < dg) {
        int s0 = esrc[r0 + k];
        h8 e0 = xp[s0];
        float4 a0 = make_float4((float)e0[0], (float)e0[1], (float)e0[2], (float)e0[3]);
        float dx0 = (float)e0[4] - pdx, dy0 = (float)e0[5] - pdy, dz0 = (float)e0[6] - pdz;
        float dist0 = sqrtf(fmaf(dx0, dx0, fmaf(dy0, dy0, dz0*dz0)));
        edge_contrib(sw1, hd, a0, dist0, acc);
    }

    // ---- Phase C: node MLP + softmax + pooling ----
    float c = (float)dg;
    float inv = fast_rcp(fmaxf(c, 1.0f));
    float h[16];
    #pragma unroll
    for (int j = 0; j < 16; ++j) h[j] = c * sb2[j];
    #pragma unroll
    for (int i = 0; i < 16; ++i) {
        float f = acc[i];
        #pragma unroll
        for (int j4 = 0; j4 < 4; ++j4) {
            float4 w = *(const float4*)&sw2[i*16 + 4*j4];
            h[4*j4+0] = fmaf(f, w.x, h[4*j4+0]);
            h[4*j4+1] = fmaf(f, w.y, h[4*j4+1]);
            h[4*j4+2] = fmaf(f, w.z, h[4*j4+2]);
            h[4*j4+3] = fmaf(f, w.w, h[4*j4+3]);
        }
    }
    #pragma unroll
    for (int j = 0; j < 16; ++j) h[j] = fmaxf(h[j] * inv, 0.0f);

    float l0 = spb[0], l1 = spb[1];
    #pragma unroll
    for (int j = 0; j < 16; ++j) {
        l0 = fmaf(h[j], spw[2*j+0], l0);
        l1 = fmaf(h[j], spw[2*j+1], l1);
    }
    float m = fmaxf(l0, l1);
    float e0 = __expf(l0 - m), e1 = __expf(l1 - m);
    float r = fast_rcp(e0 + e1);
    float s0 = e0 * r, s1 = e1 * r;
    s_out[2*n+0] = s0;
    s_out[2*n+1] = s1;

    float w[32];
    #pragma unroll
    for (int j = 0; j < 16; ++j) { w[j] = s0 * h[j]; w[16+j] = s1 * h[j]; }

    int b = batch[n];
    #pragma unroll
    for (int o = 1; o < 64; o <<= 1) {
        int bn = __shfl_down(b, o);
        bool take = (lane + o < 64) && (bn == b);
        #pragma unroll
        for (int cc = 0; cc < 32; ++cc) {
            float vn = __shfl_down(w[cc], o);
            if (take) w[cc] += vn;
        }
    }
    int bp = __shfl_up(b, 1);
    if (lane == 0 || bp != b) {
        float* pg = pooled + 32*b;
        #pragma unroll
        for (int cc = 0; cc < 32; ++cc) unsafeAtomicAdd(pg + cc, w[cc]);
    }
}

// ---------------------------------------------------------------------------
// K3: per-graph heads. z, recon, analytic potential + forces.
// ---------------------------------------------------------------------------
__global__ __launch_bounds__(256) void graph_kernel(
    const float* __restrict__ pooled,
    const float* __restrict__ toz_w, const float* __restrict__ toz_b,
    const float* __restrict__ vp_w1, const float* __restrict__ vp_b1,
    const float* __restrict__ vp_w2, const float* __restrict__ vp_b2,
    const float* __restrict__ bridge_w, const float* __restrict__ bridge_b,
    float* __restrict__ out_recon, float* __restrict__ out_z,
    float* __restrict__ out_forces, float* __restrict__ out_V)
{
    int g = blockIdx.x * 256 + threadIdx.x;
    if (g >= NUM_GRAPHS) return;

    const float* P = pooled + 32*g;
    float z[8];
    #pragma unroll
    for (int k = 0; k < 2; ++k) {
        #pragma unroll
        for (int d = 0; d < 4; ++d) {
            float a = toz_b[d];
            #pragma unroll
            for (int i = 0; i < 16; ++i) a = fmaf(P[16*k+i], toz_w[4*i+d], a);
            z[4*k+d] = a;
        }
    }
    #pragma unroll
    for (int i = 0; i < 8; ++i) out_z[8*g+i] = z[i];

    #pragma unroll
    for (int j = 0; j < 32; ++j) {
        float a = bridge_b[j];
        #pragma unroll
        for (int i = 0; i < 8; ++i) a = fmaf(z[i], bridge_w[32*i+j], a);
        out_recon[32*g+j] = a;
    }

    float d0 = z[0]-z[4], d1 = z[1]-z[5];
    float dd = sqrtf(d0*d0 + d1*d1 + 1e-6f);

    float V = vp_b2[0];
    float dV = 0.0f;
    #pragma unroll
    for (int j = 0; j < 32; ++j) {
        float w1 = vp_w1[j];
        float t  = fmaf(dd, w1, vp_b1[j]);
        float et = __expf(t);
        float sp = __logf(1.0f + et);
        float sg = et / (1.0f + et);
        float w2 = vp_w2[j];
        V  = fmaf(sp, w2, V);
        dV = fmaf(sg * w1, w2, dV);
    }
    out_V[g] = V;

    float scale = dV / dd;
    float gx = scale * d0, gy = scale * d1;
    out_forces[4*g+0] = -gx;
    out_forces[4*g+1] = -gy;
    out_forces[4*g+2] =  gx;
    out_forces[4*g+3] =  gy;
}

// ---------------------------------------------------------------------------
extern "C" void kernel_launch(void* const* d_in, const int* in_sizes, int n_in,
                              void* d_out, int out_size, void* d_ws, size_t ws_size,
                              hipStream_t stream) {
    const float* x        = (const float*)d_in[0];
    const float* pos      = (const float*)d_in[1];
    const int*   ei       = (const int*)  d_in[2];
    const int*   batch    = (const int*)  d_in[3];
    const float* enc_w1   = (const float*)d_in[4];
    const float* enc_b1   = (const float*)d_in[5];
    const float* enc_w2   = (const float*)d_in[6];
    const float* enc_b2   = (const float*)d_in[7];
    const float* pool_w   = (const float*)d_in[8];
    const float* pool_b   = (const float*)d_in[9];
    const float* toz_w    = (const float*)d_in[10];
    const float* toz_b    = (const float*)d_in[11];
    const float* vp_w1    = (const float*)d_in[12];
    const float* vp_b1    = (const float*)d_in[13];
    const float* vp_w2    = (const float*)d_in[14];
    const float* vp_b2    = (const float*)d_in[15];
    const float* bridge_w = (const float*)d_in[16];
    const float* bridge_b = (const float*)d_in[17];

    // workspace layout (4B units), ~26 MB
    int*   cursor = (int*)d_ws;                              // 256*32 (padded)
    float* pooled = (float*)d_ws + NBKT*CSTRIDE;             // 32768
    int*   staged = (int*)d_ws + NBKT*CSTRIDE + 32768;       // 256*17408
    h8*    xp     = (h8*)(staged + (size_t)NBKT*CAPK);       // 262144 * 16B = 4MB

    float* out        = (float*)d_out;
    float* out_recon  = out;                        // 1024*32
    float* out_z      = out_recon + 1024*32;        // 1024*8
    float* out_s      = out_z + 1024*8;             // 262144*2
    float* out_forces = out_s + (size_t)N_NODES*2;  // 1024*4
    float* out_V      = out_forces + 1024*4;        // 1024

    hipMemsetAsync(d_ws, 0, (size_t)(NBKT*CSTRIDE + 32768) * sizeof(float), stream);

    bin_pack_kernel<<<N_EDGES/EPB, 256, 0, stream>>>(ei, x, pos, cursor, staged, xp);
    fused_node_kernel<<<NBKT, 1024, 0, stream>>>(
        xp, cursor, staged, batch,
        enc_w1, enc_b1, enc_w2, enc_b2, pool_w, pool_b, out_s, pooled);
    graph_kernel<<<NUM_GRAPHS/256, 256, 0, stream>>>(
        pooled, toz_w, toz_b, vp_w1, vp_b1, vp_w2, vp_b2,
        bridge_w, bridge_b, out_recon, out_z, out_forces, out_V);
}

// Round 13
// 212.274 us; speedup vs baseline: 1.5529x; 1.0215x over previous
//
#include <hip/hip_runtime.h>
#include <math.h>

#define N_NODES   262144
#define N_EDGES   4194304
#define NUM_GRAPHS 1024
#define NBKT      256          // buckets (dst >> 10), 1024 nodes each
#define BNODE     1024         // nodes per fused block (FULL bucket, no filter)
#define CAPK      17408        // bucket capacity (mean 16384, +8 sigma)
#define EPB       8192         // edges per binning block
#define CSTRIDE   32           // cursor padding: 1 cursor per 128B line

typedef _Float16 h8 __attribute__((ext_vector_type(8)));

static __device__ __forceinline__ float fast_rcp(float v) {
    return __builtin_amdgcn_rcpf(v);
}

// ---------------------------------------------------------------------------
// K1: one-pass binning + fp16 packing. v2: 512-THREAD blocks (same EPB) ->
// 2 blocks/CU = 16 waves/CU (was 8). The kernel is latency-laden (cursor
// atomics ~512 serialized RMW/addr, scattered write-out, dependent rank
// chain); doubling resident waves doubles hiding. Cursor-atomic count and
// 128B write segments unchanged (r8 showed those are the cliffs).
// ---------------------------------------------------------------------------
__global__ __launch_bounds__(512) void bin_pack_kernel(
    const int* __restrict__ ei, const float* __restrict__ x,
    const float* __restrict__ pos,
    int* __restrict__ cursor, int* __restrict__ staged,
    h8* __restrict__ xp)
{
    __shared__ int cnt[NBKT], rcnt[NBKT], lbase[NBKT], gbase[NBKT];
    __shared__ int stage[EPB];                 // 32 KB
    __shared__ int wsum[4];
    int tid = threadIdx.x;
    if (tid < NBKT) { cnt[tid] = 0; rcnt[tid] = 0; }
    __syncthreads();

    // ---- pack 512 nodes (1 per thread) as fp16 records ----
    {
        int n0 = blockIdx.x * 512 + tid;
        float4 xv0 = *(const float4*)(x + 4*n0);
        h8 o0;
        o0[0] = (_Float16)xv0.x; o0[1] = (_Float16)xv0.y;
        o0[2] = (_Float16)xv0.z; o0[3] = (_Float16)xv0.w;
        o0[4] = (_Float16)pos[3*n0+0]; o0[5] = (_Float16)pos[3*n0+1];
        o0[6] = (_Float16)pos[3*n0+2]; o0[7] = (_Float16)0.0f;
        xp[n0] = o0;
    }

    // ---- histogram (16 edges/thread; dst kept in regs for rank pass) ----
    int base = blockIdx.x * EPB;
    const int4* d4 = (const int4*)(ei + N_EDGES + base);
    const int4* s4 = (const int4*)(ei + base);
    int4 dv[4];
    #pragma unroll
    for (int i = 0; i < 4; ++i) {
        dv[i] = d4[i*512 + tid];
        atomicAdd(&cnt[dv[i].x >> 10], 1);
        atomicAdd(&cnt[dv[i].y >> 10], 1);
        atomicAdd(&cnt[dv[i].z >> 10], 1);
        atomicAdd(&cnt[dv[i].w >> 10], 1);
    }
    __syncthreads();

    // ---- local exclusive scan (bins handled by threads 0..255) ----
    int lane = tid & 63, wid = tid >> 6;
    if (tid < NBKT) {
        int c = cnt[tid];
        int inc = c;
        #pragma unroll
        for (int o = 1; o < 64; o <<= 1) {
            int t = __shfl_up(inc, o);
            if (lane >= o) inc += t;
        }
        if (lane == 63) wsum[wid] = inc;
        cnt[tid] = inc;                        // stash inclusive scan
    }
    __syncthreads();
    if (tid < NBKT) {
        int inc = cnt[tid];
        int c   = inc;                         // recover c below via shfl? no:
        // recompute c from neighbors is messy; reload original count instead
        // (inc - exclusive-of-this-wave gives it, but simpler: lbase diff)
        int wb = 0;
        #pragma unroll
        for (int w = 0; w < 4; ++w) if (w < wid) wb += wsum[w];
        int prev = __shfl_up(inc, 1);          // inclusive of tid-1 (same wave)
        int excl = (lane == 0) ? 0 : prev;
        lbase[tid] = wb + excl;
        c = inc - excl;
        gbase[tid] = c ? atomicAdd(cursor + tid*CSTRIDE, c) : 0;
        rcnt[tid] = 0;
    }
    __syncthreads();

    // ---- rank + stage: ((dst&1023)<<18) | src ----
    #pragma unroll
    for (int i = 0; i < 4; ++i) {
        int4 sv = s4[i*512 + tid];
        int d, s, bk, r;
        d = dv[i].x; s = sv.x; bk = d >> 10; r = atomicAdd(&rcnt[bk], 1);
        stage[lbase[bk] + r] = ((d & 1023) << 18) | s;
        d = dv[i].y; s = sv.y; bk = d >> 10; r = atomicAdd(&rcnt[bk], 1);
        stage[lbase[bk] + r] = ((d & 1023) << 18) | s;
        d = dv[i].z; s = sv.z; bk = d >> 10; r = atomicAdd(&rcnt[bk], 1);
        stage[lbase[bk] + r] = ((d & 1023) << 18) | s;
        d = dv[i].w; s = sv.w; bk = d >> 10; r = atomicAdd(&rcnt[bk], 1);
        stage[lbase[bk] + r] = ((d & 1023) << 18) | s;
    }
    __syncthreads();

    // ---- write-out: 32 lanes per bin, 16 groups, ~128B segments ----
    int sub = tid & 31;
    int grp = tid >> 5;                        // 16 groups of 32 lanes
    #pragma unroll
    for (int pass = 0; pass < NBKT/16; ++pass) {
        int bk  = pass*16 + grp;
        int c2  = rcnt[bk];
        int lb  = lbase[bk];
        int gb  = gbase[bk];
        int lim = CAPK - gb; if (c2 > lim) c2 = lim;   // ~8-sigma guard
        for (int k = sub; k < c2; k += 32)
            staged[bk*CAPK + gb + k] = stage[lb + k];
    }
}

// ---------------------------------------------------------------------------
// Per-edge contribution: rows 4..7 (x[src]) + row 8 (dist) of enc_w1, on top
// of the per-node precomputed hd[] (bias + dst rows). silu accumulate.
// ---------------------------------------------------------------------------
static __device__ __forceinline__ void edge_contrib(
    const float* __restrict__ sw1, const float* __restrict__ hd,
    float4 xs, float dist, float* __restrict__ acc)
{
    float h[16];
    #pragma unroll
    for (int j4 = 0; j4 < 4; ++j4) {
        float4 w = *(const float4*)&sw1[4*16 + 4*j4];
        h[4*j4+0] = fmaf(xs.x, w.x, hd[4*j4+0]);
        h[4*j4+1] = fmaf(xs.x, w.y, hd[4*j4+1]);
        h[4*j4+2] = fmaf(xs.x, w.z, hd[4*j4+2]);
        h[4*j4+3] = fmaf(xs.x, w.w, hd[4*j4+3]);
    }
    #pragma unroll
    for (int j4 = 0; j4 < 4; ++j4) {
        float4 w = *(const float4*)&sw1[5*16 + 4*j4];
        h[4*j4+0] = fmaf(xs.y, w.x, h[4*j4+0]);
        h[4*j4+1] = fmaf(xs.y, w.y, h[4*j4+1]);
        h[4*j4+2] = fmaf(xs.y, w.z, h[4*j4+2]);
        h[4*j4+3] = fmaf(xs.y, w.w, h[4*j4+3]);
    }
    #pragma unroll
    for (int j4 = 0; j4 < 4; ++j4) {
        float4 w = *(const float4*)&sw1[6*16 + 4*j4];
        h[4*j4+0] = fmaf(xs.z, w.x, h[4*j4+0]);
        h[4*j4+1] = fmaf(xs.z, w.y, h[4*j4+1]);
        h[4*j4+2] = fmaf(xs.z, w.z, h[4*j4+2]);
        h[4*j4+3] = fmaf(xs.z, w.w, h[4*j4+3]);
    }
    #pragma unroll
    for (int j4 = 0; j4 < 4; ++j4) {
        float4 w = *(const float4*)&sw1[7*16 + 4*j4];
        h[4*j4+0] = fmaf(xs.w, w.x, h[4*j4+0]);
        h[4*j4+1] = fmaf(xs.w, w.y, h[4*j4+1]);
        h[4*j4+2] = fmaf(xs.w, w.z, h[4*j4+2]);
        h[4*j4+3] = fmaf(xs.w, w.w, h[4*j4+3]);
    }
    #pragma unroll
    for (int j4 = 0; j4 < 4; ++j4) {
        float4 w = *(const float4*)&sw1[8*16 + 4*j4];
        h[4*j4+0] = fmaf(dist, w.x, h[4*j4+0]);
        h[4*j4+1] = fmaf(dist, w.y, h[4*j4+1]);
        h[4*j4+2] = fmaf(dist, w.z, h[4*j4+2]);
        h[4*j4+3] = fmaf(dist, w.w, h[4*j4+3]);
    }
    #pragma unroll
    for (int j = 0; j < 16; ++j) {
        float sg = fast_rcp(1.0f + __expf(-h[j]));
        acc[j] = fmaf(h[j], sg, acc[j]);
    }
}

// ---------------------------------------------------------------------------
// K2 (fused): r12 structure + NON-TEMPORAL staged reads. staged streams 32MB
// through L2 and was evicting the 4MB xp record array (FETCH 118MB >> 36MB
// unique); nt loads mark staged lines for early eviction, protecting xp
// residency so the random 16B gathers become L2 hits.
// ---------------------------------------------------------------------------
__global__ __launch_bounds__(1024, 4) void fused_node_kernel(
    const h8* __restrict__ xp,
    const int* __restrict__ cursor, const int* __restrict__ staged,
    const int* __restrict__ batch,
    const float* __restrict__ w1, const float* __restrict__ b1,
    const float* __restrict__ w2, const float* __restrict__ b2,
    const float* __restrict__ pw, const float* __restrict__ pb,
    float* __restrict__ s_out, float* __restrict__ pooled)
{
    __shared__ int esrc[CAPK];                 // 69632 B
    __shared__ int ldeg[BNODE];                // 4096 B (hist, then cursor)
    __shared__ int wsum[16];
    __shared__ __align__(16) float sw1[144];
    __shared__ float sb1[16];
    __shared__ __align__(16) float sw2[256];
    __shared__ float sb2[16];
    __shared__ float spw[32];
    __shared__ float spb[2];

    int tid = threadIdx.x;
    if (tid < 144) sw1[tid] = w1[tid];
    if (tid >= 144 && tid < 160) sb1[tid - 144] = b1[tid - 144];
    if (tid >= 160 && tid < 176) sb2[tid - 160] = b2[tid - 160];
    if (tid >= 176 && tid < 208) spw[tid - 176] = pw[tid - 176];
    if (tid >= 208 && tid < 210) spb[tid - 208] = pb[tid - 208];
    if (tid >= 256 && tid < 512) sw2[tid - 256] = w2[tid - 256];
    ldeg[tid] = 0;
    __syncthreads();

    int bkt  = blockIdx.x;
    int cnt  = cursor[bkt*CSTRIDE]; if (cnt > CAPK) cnt = CAPK;
    int base = bkt * CAPK;
    int nb0  = bkt * BNODE;

    // ---- Phase A: counting sort into LDS (nt loads protect xp in L2) ----
    for (int i = tid; i < cnt; i += 1024)
        atomicAdd(&ldeg[__builtin_nontemporal_load(&staged[base + i]) >> 18], 1);
    __syncthreads();

    int dg   = ldeg[tid];                      // degree of node nb0+tid
    int lane = tid & 63, wid = tid >> 6;       // wid 0..15
    int inc  = dg;
    #pragma unroll
    for (int o = 1; o < 64; o <<= 1) {
        int t = __shfl_up(inc, o);
        if (lane >= o) inc += t;
    }
    if (lane == 63) wsum[wid] = inc;
    __syncthreads();
    int wb = 0;
    #pragma unroll
    for (int w = 0; w < 16; ++w) if (w < wid) wb += wsum[w];
    int r0 = wb + inc - dg;                    // exclusive row offset in esrc
    ldeg[tid] = r0;                            // reuse as scatter cursor
    __syncthreads();

    for (int i = tid; i < cnt; i += 1024) {
        int p  = __builtin_nontemporal_load(&staged[base + i]);
        int lo = p >> 18;
        int r  = atomicAdd(&ldeg[lo], 1);
        esrc[r] = p & 0x3FFFF;
    }
    __syncthreads();

    // ---- Phase B: per-node gather + edge MLP ----
    int n = nb0 + tid;
    h8 rd = xp[n];
    float4 xd = make_float4((float)rd[0], (float)rd[1], (float)rd[2], (float)rd[3]);
    float pdx = (float)rd[4], pdy = (float)rd[5], pdz = (float)rd[6];

    // hd[j] = b1[j] + sum_{i<4} xd_i * w1[i][j]  -- hoisted out of edge loop
    float hd[16];
    #pragma unroll
    for (int j = 0; j < 16; ++j) hd[j] = sb1[j];
    #pragma unroll
    for (int j4 = 0; j4 < 4; ++j4) {
        float4 w0 = *(const float4*)&sw1[0*16 + 4*j4];
        float4 w1r = *(const float4*)&sw1[1*16 + 4*j4];
        float4 w2r = *(const float4*)&sw1[2*16 + 4*j4];
        float4 w3r = *(const float4*)&sw1[3*16 + 4*j4];
        hd[4*j4+0] = fmaf(xd.x, w0.x, hd[4*j4+0]);
        hd[4*j4+1] = fmaf(xd.x, w0.y, hd[4*j4+1]);
        hd[4*j4+2] = fmaf(xd.x, w0.z, hd[4*j4+2]);
        hd[4*j4+3] = fmaf(xd.x, w0.w, hd[4*j4+3]);
        hd[4*j4+0] = fmaf(xd.y, w1r.x, hd[4*j4+0]);
        hd[4*j4+1] = fmaf(xd.y, w1r.y, hd[4*j4+1]);
        hd[4*j4+2] = fmaf(xd.y, w1r.z, hd[4*j4+2]);
        hd[4*j4+3] = fmaf(xd.y, w1r.w, hd[4*j4+3]);
        hd[4*j4+0] = fmaf(xd.z, w2r.x, hd[4*j4+0]);
        hd[4*j4+1] = fmaf(xd.z, w2r.y, hd[4*j4+1]);
        hd[4*j4+2] = fmaf(xd.z, w2r.z, hd[4*j4+2]);
        hd[4*j4+3] = fmaf(xd.z, w2r.w, hd[4*j4+3]);
        hd[4*j4+0] = fmaf(xd.w, w3r.x, hd[4*j4+0]);
        hd[4*j4+1] = fmaf(xd.w, w3r.y, hd[4*j4+1]);
        hd[4*j4+2] = fmaf(xd.w, w3r.z, hd[4*j4+2]);
        hd[4*j4+3] = fmaf(xd.w, w3r.w, hd[4*j4+3]);
    }

    float acc[16];
    #pragma unroll
    for (int j = 0; j < 16; ++j) acc[j] = 0.0f;

    int k = 0;
    for (; k + 2 <= dg; k += 2) {
        int s0 = esrc[r0 + k];
        int s1 = esrc[r0 + k + 1];
        h8 e0 = xp[s0];
        h8 e1 = xp[s1];

        float4 a0 = make_float4((float)e0[0], (float)e0[1], (float)e0[2], (float)e0[3]);
        float dx0 = (float)e0[4] - pdx, dy0 = (float)e0[5] - pdy, dz0 = (float)e0[6] - pdz;
        float dist0 = sqrtf(fmaf(dx0, dx0, fmaf(dy0, dy0, dz0*dz0)));
        edge_contrib(sw1, hd, a0, dist0, acc);

        float4 a1 = make_float4((float)e1[0], (float)e1[1], (float)e1[2], (float)e1[3]);
        float dx1 = (float)e1[4] - pdx, dy1 = (float)e1[5] - pdy, dz1 = (float)e1[6] - pdz;
        float dist1 = sqrtf(fmaf(dx1, dx1, fmaf(dy1, dy1, dz1*dz1)));
        edge_contrib(sw1, hd, a1, dist1, acc);
    }
    if (k < dg) {
        int s0 = esrc[r0 + k];
        h8 e0 = xp[s0];
        float4 a0 = make_float4((float)e0[0], (float)e0[1], (float)e0[2], (float)e0[3]);
        float dx0 = (float)e0[4] - pdx, dy0 = (float)e0[5] - pdy, dz0 = (float)e0[6] - pdz;
        float dist0 = sqrtf(fmaf(dx0, dx0, fmaf(dy0, dy0, dz0*dz0)));
        edge_contrib(sw1, hd, a0, dist0, acc);
    }

    // ---- Phase C: node MLP + softmax + pooling ----
    float c = (float)dg;
    float inv = fast_rcp(fmaxf(c, 1.0f));
    float h[16];
    #pragma unroll
    for (int j = 0; j < 16; ++j) h[j] = c * sb2[j];
    #pragma unroll
    for (int i = 0; i < 16; ++i) {
        float f = acc[i];
        #pragma unroll
        for (int j4 = 0; j4 < 4; ++j4) {
            float4 w = *(const float4*)&sw2[i*16 + 4*j4];
            h[4*j4+0] = fmaf(f, w.x, h[4*j4+0]);
            h[4*j4+1] = fmaf(f, w.y, h[4*j4+1]);
            h[4*j4+2] = fmaf(f, w.z, h[4*j4+2]);
            h[4*j4+3] = fmaf(f, w.w, h[4*j4+3]);
        }
    }
    #pragma unroll
    for (int j = 0; j < 16; ++j) h[j] = fmaxf(h[j] * inv, 0.0f);

    float l0 = spb[0], l1 = spb[1];
    #pragma unroll
    for (int j = 0; j < 16; ++j) {
        l0 = fmaf(h[j], spw[2*j+0], l0);
        l1 = fmaf(h[j], spw[2*j+1], l1);
    }
    float m = fmaxf(l0, l1);
    float e0 = __expf(l0 - m), e1 = __expf(l1 - m);
    float r = fast_rcp(e0 + e1);
    float s0 = e0 * r, s1 = e1 * r;
    s_out[2*n+0] = s0;
    s_out[2*n+1] = s1;

    float w[32];
    #pragma unroll
    for (int j = 0; j < 16; ++j) { w[j] = s0 * h[j]; w[16+j] = s1 * h[j]; }

    int b = batch[n];
    #pragma unroll
    for (int o = 1; o < 64; o <<= 1) {
        int bn = __shfl_down(b, o);
        bool take = (lane + o < 64) && (bn == b);
        #pragma unroll
        for (int cc = 0; cc < 32; ++cc) {
            float vn = __shfl_down(w[cc], o);
            if (take) w[cc] += vn;
        }
    }
    int bp = __shfl_up(b, 1);
    if (lane == 0 || bp != b) {
        float* pg = pooled + 32*b;
        #pragma unroll
        for (int cc = 0; cc < 32; ++cc) unsafeAtomicAdd(pg + cc, w[cc]);
    }
}

// ---------------------------------------------------------------------------
// K3: per-graph heads. z, recon, analytic potential + forces.
// ---------------------------------------------------------------------------
__global__ __launch_bounds__(256) void graph_kernel(
    const float* __restrict__ pooled,
    const float* __restrict__ toz_w, const float* __restrict__ toz_b,
    const float* __restrict__ vp_w1, const float* __restrict__ vp_b1,
    const float* __restrict__ vp_w2, const float* __restrict__ vp_b2,
    const float* __restrict__ bridge_w, const float* __restrict__ bridge_b,
    float* __restrict__ out_recon, float* __restrict__ out_z,
    float* __restrict__ out_forces, float* __restrict__ out_V)
{
    int g = blockIdx.x * 256 + threadIdx.x;
    if (g >= NUM_GRAPHS) return;

    const float* P = pooled + 32*g;
    float z[8];
    #pragma unroll
    for (int k = 0; k < 2; ++k) {
        #pragma unroll
        for (int d = 0; d < 4; ++d) {
            float a = toz_b[d];
            #pragma unroll
            for (int i = 0; i < 16; ++i) a = fmaf(P[16*k+i], toz_w[4*i+d], a);
            z[4*k+d] = a;
        }
    }
    #pragma unroll
    for (int i = 0; i < 8; ++i) out_z[8*g+i] = z[i];

    #pragma unroll
    for (int j = 0; j < 32; ++j) {
        float a = bridge_b[j];
        #pragma unroll
        for (int i = 0; i < 8; ++i) a = fmaf(z[i], bridge_w[32*i+j], a);
        out_recon[32*g+j] = a;
    }

    float d0 = z[0]-z[4], d1 = z[1]-z[5];
    float dd = sqrtf(d0*d0 + d1*d1 + 1e-6f);

    float V = vp_b2[0];
    float dV = 0.0f;
    #pragma unroll
    for (int j = 0; j < 32; ++j) {
        float w1 = vp_w1[j];
        float t  = fmaf(dd, w1, vp_b1[j]);
        float et = __expf(t);
        float sp = __logf(1.0f + et);
        float sg = et / (1.0f + et);
        float w2 = vp_w2[j];
        V  = fmaf(sp, w2, V);
        dV = fmaf(sg * w1, w2, dV);
    }
    out_V[g] = V;

    float scale = dV / dd;
    float gx = scale * d0, gy = scale * d1;
    out_forces[4*g+0] = -gx;
    out_forces[4*g+1] = -gy;
    out_forces[4*g+2] =  gx;
    out_forces[4*g+3] =  gy;
}

// ---------------------------------------------------------------------------
extern "C" void kernel_launch(void* const* d_in, const int* in_sizes, int n_in,
                              void* d_out, int out_size, void* d_ws, size_t ws_size,
                              hipStream_t stream) {
    const float* x        = (const float*)d_in[0];
    const float* pos      = (const float*)d_in[1];
    const int*   ei       = (const int*)  d_in[2];
    const int*   batch    = (const int*)  d_in[3];
    const float* enc_w1   = (const float*)d_in[4];
    const float* enc_b1   = (const float*)d_in[5];
    const float* enc_w2   = (const float*)d_in[6];
    const float* enc_b2   = (const float*)d_in[7];
    const float* pool_w   = (const float*)d_in[8];
    const float* pool_b   = (const float*)d_in[9];
    const float* toz_w    = (const float*)d_in[10];
    const float* toz_b    = (const float*)d_in[11];
    const float* vp_w1    = (const float*)d_in[12];
    const float* vp_b1    = (const float*)d_in[13];
    const float* vp_w2    = (const float*)d_in[14];
    const float* vp_b2    = (const float*)d_in[15];
    const float* bridge_w = (const float*)d_in[16];
    const float* bridge_b = (const float*)d_in[17];

    // workspace layout (4B units), ~26 MB
    int*   cursor = (int*)d_ws;                              // 256*32 (padded)
    float* pooled = (float*)d_ws + NBKT*CSTRIDE;             // 32768
    int*   staged = (int*)d_ws + NBKT*CSTRIDE + 32768;       // 256*17408
    h8*    xp     = (h8*)(staged + (size_t)NBKT*CAPK);       // 262144 * 16B = 4MB

    float* out        = (float*)d_out;
    float* out_recon  = out;                        // 1024*32
    float* out_z      = out_recon + 1024*32;        // 1024*8
    float* out_s      = out_z + 1024*8;             // 262144*2
    float* out_forces = out_s + (size_t)N_NODES*2;  // 1024*4
    float* out_V      = out_forces + 1024*4;        // 1024

    hipMemsetAsync(d_ws, 0, (size_t)(NBKT*CSTRIDE + 32768) * sizeof(float), stream);

    bin_pack_kernel<<<N_EDGES/EPB, 512, 0, stream>>>(ei, x, pos, cursor, staged, xp);
    fused_node_kernel<<<NBKT, 1024, 0, stream>>>(
        xp, cursor, staged, batch,
        enc_w1, enc_b1, enc_w2, enc_b2, pool_w, pool_b, out_s, pooled);
    graph_kernel<<<NUM_GRAPHS/256, 256, 0, stream>>>(
        pooled, toz_w, toz_b, vp_w1, vp_b1, vp_w2, vp_b2,
        bridge_w, bridge_b, out_recon, out_z, out_forces, out_V);
}

// Round 14
// 212.053 us; speedup vs baseline: 1.5545x; 1.0010x over previous
//
#include <hip/hip_runtime.h>
#include <math.h>

#define N_NODES   262144
#define N_EDGES   4194304
#define NUM_GRAPHS 1024
#define NBKT      256          // buckets (dst >> 10), 1024 nodes each
#define BNODE     1024         // nodes per fused block (full bucket)
#define CAPK      17408        // bucket total capacity for esrc (mean 16384, +8 sigma)
#define NBLK      256          // bin_pack blocks
#define EPB       16384        // edges per bin_pack block
#define SEGCAP    112          // per-(bucket,block) segment cap (mean 64, +6 sigma; max obs ~101)

typedef _Float16 h8 __attribute__((ext_vector_type(8)));

static __device__ __forceinline__ float fast_rcp(float v) {
    return __builtin_amdgcn_rcpf(v);
}

// ---------------------------------------------------------------------------
// K1: binning v4 -- deterministic fixed segments. Each block writes bucket
// bk's edges at staged[(bk*NBLK + blk)*SEGCAP .. +cnt), cnt in cnts[bk*NBLK+blk].
// NO global cursor (r8: 512-deep atomic serialization/addr), NO memset
// dependency (cnts fully overwritten; pooled zeroed here; cursor gone).
// 1024 thr x 16384 edges; segments avg 64 ints = 256B = full L2 sectors.
// Also packs fp16 node records (r12: xp 4MB = L2-resident gathers).
// ---------------------------------------------------------------------------
__global__ __launch_bounds__(1024) void bin_pack_kernel(
    const int* __restrict__ ei, const float* __restrict__ x,
    const float* __restrict__ pos,
    int* __restrict__ cnts, int* __restrict__ staged,
    h8* __restrict__ xp, float* __restrict__ pooled)
{
    __shared__ int cnt[NBKT], rcnt[NBKT], lbase[NBKT];
    __shared__ int wsum[4];
    __shared__ int stage[EPB];                 // 64 KB
    int tid = threadIdx.x;
    if (tid < NBKT) { cnt[tid] = 0; rcnt[tid] = 0; }
    __syncthreads();

    // ---- pack 1024 nodes (1/thread) as fp16 records; zero pooled ----
    {
        int n0 = blockIdx.x * 1024 + tid;
        float4 xv = *(const float4*)(x + 4*n0);
        h8 o;
        o[0] = (_Float16)xv.x; o[1] = (_Float16)xv.y;
        o[2] = (_Float16)xv.z; o[3] = (_Float16)xv.w;
        o[4] = (_Float16)pos[3*n0+0]; o[5] = (_Float16)pos[3*n0+1];
        o[6] = (_Float16)pos[3*n0+2]; o[7] = (_Float16)0.0f;
        xp[n0] = o;
        if (blockIdx.x < 32) pooled[blockIdx.x*1024 + tid] = 0.0f;
    }

    // ---- histogram (dst kept in regs for rank pass) ----
    int base = blockIdx.x * EPB;
    const int4* d4 = (const int4*)(ei + N_EDGES + base);
    const int4* s4 = (const int4*)(ei + base);
    int4 dv[4];
    #pragma unroll
    for (int i = 0; i < 4; ++i) {
        dv[i] = d4[i*1024 + tid];
        atomicAdd(&cnt[dv[i].x >> 10], 1);
        atomicAdd(&cnt[dv[i].y >> 10], 1);
        atomicAdd(&cnt[dv[i].z >> 10], 1);
        atomicAdd(&cnt[dv[i].w >> 10], 1);
    }
    __syncthreads();

    // ---- local exclusive scan over 256 bins (threads 0..255 = waves 0..3) ----
    int lane = tid & 63, wid = tid >> 6;
    if (tid < NBKT) {
        int inc = cnt[tid];
        #pragma unroll
        for (int o = 1; o < 64; o <<= 1) {
            int t = __shfl_up(inc, o);
            if (lane >= o) inc += t;
        }
        if (lane == 63) wsum[wid] = inc;
        cnt[tid] = inc;                        // stash inclusive scan
    }
    __syncthreads();
    if (tid < NBKT) {
        int inc  = cnt[tid];
        int prev = __shfl_up(inc, 1);
        int excl = (lane == 0) ? 0 : prev;
        int wb = 0;
        #pragma unroll
        for (int w = 0; w < 4; ++w) if (w < wid) wb += wsum[w];
        lbase[tid] = wb + excl;
    }
    __syncthreads();

    // ---- rank + stage: ((dst&1023)<<18) | src ----
    #pragma unroll
    for (int i = 0; i < 4; ++i) {
        int4 sv = s4[i*1024 + tid];
        int d, s, bk, r;
        d = dv[i].x; s = sv.x; bk = d >> 10; r = atomicAdd(&rcnt[bk], 1);
        stage[lbase[bk] + r] = ((d & 1023) << 18) | s;
        d = dv[i].y; s = sv.y; bk = d >> 10; r = atomicAdd(&rcnt[bk], 1);
        stage[lbase[bk] + r] = ((d & 1023) << 18) | s;
        d = dv[i].z; s = sv.z; bk = d >> 10; r = atomicAdd(&rcnt[bk], 1);
        stage[lbase[bk] + r] = ((d & 1023) << 18) | s;
        d = dv[i].w; s = sv.w; bk = d >> 10; r = atomicAdd(&rcnt[bk], 1);
        stage[lbase[bk] + r] = ((d & 1023) << 18) | s;
    }
    __syncthreads();

    // ---- write-out to FIXED segments: 32 lanes/bin, 32 groups, 8 passes ----
    int sub = tid & 31, grp = tid >> 5;
    #pragma unroll
    for (int pass = 0; pass < NBKT/32; ++pass) {
        int bk  = pass*32 + grp;
        int c2  = rcnt[bk];
        int lb  = lbase[bk];
        if (c2 > SEGCAP) c2 = SEGCAP;          // deterministic input: never hit
        size_t sb = ((size_t)bk*NBLK + blockIdx.x)*SEGCAP;
        for (int k = sub; k < c2; k += 32)
            staged[sb + k] = stage[lb + k];
        if (sub == 0) cnts[bk*NBLK + blockIdx.x] = c2;
    }
}

// ---------------------------------------------------------------------------
// Per-edge contribution: rows 4..7 (x[src]) + row 8 (dist) of enc_w1, on top
// of the per-node precomputed hd[] (bias + dst rows). silu accumulate.
// ---------------------------------------------------------------------------
static __device__ __forceinline__ void edge_contrib(
    const float* __restrict__ sw1, const float* __restrict__ hd,
    float4 xs, float dist, float* __restrict__ acc)
{
    float h[16];
    #pragma unroll
    for (int j4 = 0; j4 < 4; ++j4) {
        float4 w = *(const float4*)&sw1[4*16 + 4*j4];
        h[4*j4+0] = fmaf(xs.x, w.x, hd[4*j4+0]);
        h[4*j4+1] = fmaf(xs.x, w.y, hd[4*j4+1]);
        h[4*j4+2] = fmaf(xs.x, w.z, hd[4*j4+2]);
        h[4*j4+3] = fmaf(xs.x, w.w, hd[4*j4+3]);
    }
    #pragma unroll
    for (int j4 = 0; j4 < 4; ++j4) {
        float4 w = *(const float4*)&sw1[5*16 + 4*j4];
        h[4*j4+0] = fmaf(xs.y, w.x, h[4*j4+0]);
        h[4*j4+1] = fmaf(xs.y, w.y, h[4*j4+1]);
        h[4*j4+2] = fmaf(xs.y, w.z, h[4*j4+2]);
        h[4*j4+3] = fmaf(xs.y, w.w, h[4*j4+3]);
    }
    #pragma unroll
    for (int j4 = 0; j4 < 4; ++j4) {
        float4 w = *(const float4*)&sw1[6*16 + 4*j4];
        h[4*j4+0] = fmaf(xs.z, w.x, h[4*j4+0]);
        h[4*j4+1] = fmaf(xs.z, w.y, h[4*j4+1]);
        h[4*j4+2] = fmaf(xs.z, w.z, h[4*j4+2]);
        h[4*j4+3] = fmaf(xs.z, w.w, h[4*j4+3]);
    }
    #pragma unroll
    for (int j4 = 0; j4 < 4; ++j4) {
        float4 w = *(const float4*)&sw1[7*16 + 4*j4];
        h[4*j4+0] = fmaf(xs.w, w.x, h[4*j4+0]);
        h[4*j4+1] = fmaf(xs.w, w.y, h[4*j4+1]);
        h[4*j4+2] = fmaf(xs.w, w.z, h[4*j4+2]);
        h[4*j4+3] = fmaf(xs.w, w.w, h[4*j4+3]);
    }
    #pragma unroll
    for (int j4 = 0; j4 < 4; ++j4) {
        float4 w = *(const float4*)&sw1[8*16 + 4*j4];
        h[4*j4+0] = fmaf(dist, w.x, h[4*j4+0]);
        h[4*j4+1] = fmaf(dist, w.y, h[4*j4+1]);
        h[4*j4+2] = fmaf(dist, w.z, h[4*j4+2]);
        h[4*j4+3] = fmaf(dist, w.w, h[4*j4+3]);
    }
    #pragma unroll
    for (int j = 0; j < 16; ++j) {
        float sg = fast_rcp(1.0f + __expf(-h[j]));
        acc[j] = fmaf(h[j], sg, acc[j]);
    }
}

// ---------------------------------------------------------------------------
// K2 (fused): r13 core; Phase A now stitches the bucket's 256 fixed segments
// (wave w handles segments w, w+16, ... -- CLT-balanced). Phase B/C identical
// (fp16 records, 2-wide loop, 64 VGPR).
// ---------------------------------------------------------------------------
__global__ __launch_bounds__(1024, 4) void fused_node_kernel(
    const h8* __restrict__ xp,
    const int* __restrict__ cnts, const int* __restrict__ staged,
    const int* __restrict__ batch,
    const float* __restrict__ w1, const float* __restrict__ b1,
    const float* __restrict__ w2, const float* __restrict__ b2,
    const float* __restrict__ pw, const float* __restrict__ pb,
    float* __restrict__ s_out, float* __restrict__ pooled)
{
    __shared__ int esrc[CAPK];                 // 69632 B
    __shared__ int ldeg[BNODE];                // hist, then scatter cursor
    __shared__ int scnt[NBLK];                 // per-segment counts
    __shared__ int wsum[16];
    __shared__ __align__(16) float sw1[144];
    __shared__ float sb1[16];
    __shared__ __align__(16) float sw2[256];
    __shared__ float sb2[16];
    __shared__ float spw[32];
    __shared__ float spb[2];

    int tid = threadIdx.x;
    int bkt = blockIdx.x;
    if (tid < 144) sw1[tid] = w1[tid];
    if (tid >= 144 && tid < 160) sb1[tid - 144] = b1[tid - 144];
    if (tid >= 160 && tid < 176) sb2[tid - 160] = b2[tid - 160];
    if (tid >= 176 && tid < 208) spw[tid - 176] = pw[tid - 176];
    if (tid >= 208 && tid < 210) spb[tid - 208] = pb[tid - 208];
    if (tid >= 256 && tid < 512) sw2[tid - 256] = w2[tid - 256];
    if (tid >= 512 && tid < 768) scnt[tid - 512] = cnts[bkt*NBLK + (tid - 512)];
    ldeg[tid] = 0;
    __syncthreads();

    int lane = tid & 63, wid = tid >> 6;       // wid 0..15
    int nb0  = bkt * BNODE;

    // ---- Phase A1: histogram over 256 segments (wave-per-segment) ----
    for (int s = wid; s < NBLK; s += 16) {
        int c = scnt[s];
        const int* seg = staged + ((size_t)bkt*NBLK + s)*SEGCAP;
        for (int i = lane; i < c; i += 64)
            atomicAdd(&ldeg[seg[i] >> 18], 1);
    }
    __syncthreads();

    int dg  = ldeg[tid];                       // degree of node nb0+tid
    int inc = dg;
    #pragma unroll
    for (int o = 1; o < 64; o <<= 1) {
        int t = __shfl_up(inc, o);
        if (lane >= o) inc += t;
    }
    if (lane == 63) wsum[wid] = inc;
    __syncthreads();
    int wb = 0;
    #pragma unroll
    for (int w = 0; w < 16; ++w) if (w < wid) wb += wsum[w];
    int r0 = wb + inc - dg;                    // exclusive row offset in esrc
    ldeg[tid] = r0;                            // reuse as scatter cursor
    __syncthreads();

    // ---- Phase A2: scatter src ids into esrc ----
    for (int s = wid; s < NBLK; s += 16) {
        int c = scnt[s];
        const int* seg = staged + ((size_t)bkt*NBLK + s)*SEGCAP;
        for (int i = lane; i < c; i += 64) {
            int p = seg[i];
            int r = atomicAdd(&ldeg[p >> 18], 1);
            if (r < CAPK) esrc[r] = p & 0x3FFFF;
        }
    }
    __syncthreads();

    // ---- Phase B: per-node gather + edge MLP ----
    int n = nb0 + tid;
    h8 rd = xp[n];
    float4 xd = make_float4((float)rd[0], (float)rd[1], (float)rd[2], (float)rd[3]);
    float pdx = (float)rd[4], pdy = (float)rd[5], pdz = (float)rd[6];

    // hd[j] = b1[j] + sum_{i<4} xd_i * w1[i][j]  -- hoisted out of edge loop
    float hd[16];
    #pragma unroll
    for (int j = 0; j < 16; ++j) hd[j] = sb1[j];
    #pragma unroll
    for (int j4 = 0; j4 < 4; ++j4) {
        float4 w0 = *(const float4*)&sw1[0*16 + 4*j4];
        float4 w1r = *(const float4*)&sw1[1*16 + 4*j4];
        float4 w2r = *(const float4*)&sw1[2*16 + 4*j4];
        float4 w3r = *(const float4*)&sw1[3*16 + 4*j4];
        hd[4*j4+0] = fmaf(xd.x, w0.x, hd[4*j4+0]);
        hd[4*j4+1] = fmaf(xd.x, w0.y, hd[4*j4+1]);
        hd[4*j4+2] = fmaf(xd.x, w0.z, hd[4*j4+2]);
        hd[4*j4+3] = fmaf(xd.x, w0.w, hd[4*j4+3]);
        hd[4*j4+0] = fmaf(xd.y, w1r.x, hd[4*j4+0]);
        hd[4*j4+1] = fmaf(xd.y, w1r.y, hd[4*j4+1]);
        hd[4*j4+2] = fmaf(xd.y, w1r.z, hd[4*j4+2]);
        hd[4*j4+3] = fmaf(xd.y, w1r.w, hd[4*j4+3]);
        hd[4*j4+0] = fmaf(xd.z, w2r.x, hd[4*j4+0]);
        hd[4*j4+1] = fmaf(xd.z, w2r.y, hd[4*j4+1]);
        hd[4*j4+2] = fmaf(xd.z, w2r.z, hd[4*j4+2]);
        hd[4*j4+3] = fmaf(xd.z, w2r.w, hd[4*j4+3]);
        hd[4*j4+0] = fmaf(xd.w, w3r.x, hd[4*j4+0]);
        hd[4*j4+1] = fmaf(xd.w, w3r.y, hd[4*j4+1]);
        hd[4*j4+2] = fmaf(xd.w, w3r.z, hd[4*j4+2]);
        hd[4*j4+3] = fmaf(xd.w, w3r.w, hd[4*j4+3]);
    }

    float acc[16];
    #pragma unroll
    for (int j = 0; j < 16; ++j) acc[j] = 0.0f;

    int k = 0;
    for (; k + 2 <= dg; k += 2) {
        int s0 = esrc[r0 + k];
        int s1 = esrc[r0 + k + 1];
        h8 e0 = xp[s0];
        h8 e1 = xp[s1];

        float4 a0 = make_float4((float)e0[0], (float)e0[1], (float)e0[2], (float)e0[3]);
        float dx0 = (float)e0[4] - pdx, dy0 = (float)e0[5] - pdy, dz0 = (float)e0[6] - pdz;
        float dist0 = sqrtf(fmaf(dx0, dx0, fmaf(dy0, dy0, dz0*dz0)));
        edge_contrib(sw1, hd, a0, dist0, acc);

        float4 a1 = make_float4((float)e1[0], (float)e1[1], (float)e1[2], (float)e1[3]);
        float dx1 = (float)e1[4] - pdx, dy1 = (float)e1[5] - pdy, dz1 = (float)e1[6] - pdz;
        float dist1 = sqrtf(fmaf(dx1, dx1, fmaf(dy1, dy1, dz1*dz1)));
        edge_contrib(sw1, hd, a1, dist1, acc);
    }
    if (k < dg) {
        int s0 = esrc[r0 + k];
        h8 e0 = xp[s0];
        float4 a0 = make_float4((float)e0[0], (float)e0[1], (float)e0[2], (float)e0[3]);
        float dx0 = (float)e0[4] - pdx, dy0 = (float)e0[5] - pdy, dz0 = (float)e0[6] - pdz;
        float dist0 = sqrtf(fmaf(dx0, dx0, fmaf(dy0, dy0, dz0*dz0)));
        edge_contrib(sw1, hd, a0, dist0, acc);
    }

    // ---- Phase C: node MLP + softmax + pooling ----
    float c = (float)dg;
    float inv = fast_rcp(fmaxf(c, 1.0f));
    float h[16];
    #pragma unroll
    for (int j = 0; j < 16; ++j) h[j] = c * sb2[j];
    #pragma unroll
    for (int i = 0; i < 16; ++i) {
        float f = acc[i];
        #pragma unroll
        for (int j4 = 0; j4 < 4; ++j4) {
            float4 w = *(const float4*)&sw2[i*16 + 4*j4];
            h[4*j4+0] = fmaf(f, w.x, h[4*j4+0]);
            h[4*j4+1] = fmaf(f, w.y, h[4*j4+1]);
            h[4*j4+2] = fmaf(f, w.z, h[4*j4+2]);
            h[4*j4+3] = fmaf(f, w.w, h[4*j4+3]);
        }
    }
    #pragma unroll
    for (int j = 0; j < 16; ++j) h[j] = fmaxf(h[j] * inv, 0.0f);

    float l0 = spb[0], l1 = spb[1];
    #pragma unroll
    for (int j = 0; j < 16; ++j) {
        l0 = fmaf(h[j], spw[2*j+0], l0);
        l1 = fmaf(h[j], spw[2*j+1], l1);
    }
    float m = fmaxf(l0, l1);
    float e0 = __expf(l0 - m), e1 = __expf(l1 - m);
    float r = fast_rcp(e0 + e1);
    float s0 = e0 * r, s1 = e1 * r;
    s_out[2*n+0] = s0;
    s_out[2*n+1] = s1;

    float w[32];
    #pragma unroll
    for (int j = 0; j < 16; ++j) { w[j] = s0 * h[j]; w[16+j] = s1 * h[j]; }

    int b = batch[n];
    #pragma unroll
    for (int o = 1; o < 64; o <<= 1) {
        int bn = __shfl_down(b, o);
        bool take = (lane + o < 64) && (bn == b);
        #pragma unroll
        for (int cc = 0; cc < 32; ++cc) {
            float vn = __shfl_down(w[cc], o);
            if (take) w[cc] += vn;
        }
    }
    int bp = __shfl_up(b, 1);
    if (lane == 0 || bp != b) {
        float* pg = pooled + 32*b;
        #pragma unroll
        for (int cc = 0; cc < 32; ++cc) unsafeAtomicAdd(pg + cc, w[cc]);
    }
}

// ---------------------------------------------------------------------------
// K3: per-graph heads. z, recon, analytic potential + forces.
// ---------------------------------------------------------------------------
__global__ __launch_bounds__(256) void graph_kernel(
    const float* __restrict__ pooled,
    const float* __restrict__ toz_w, const float* __restrict__ toz_b,
    const float* __restrict__ vp_w1, const float* __restrict__ vp_b1,
    const float* __restrict__ vp_w2, const float* __restrict__ vp_b2,
    const float* __restrict__ bridge_w, const float* __restrict__ bridge_b,
    float* __restrict__ out_recon, float* __restrict__ out_z,
    float* __restrict__ out_forces, float* __restrict__ out_V)
{
    int g = blockIdx.x * 256 + threadIdx.x;
    if (g >= NUM_GRAPHS) return;

    const float* P = pooled + 32*g;
    float z[8];
    #pragma unroll
    for (int k = 0; k < 2; ++k) {
        #pragma unroll
        for (int d = 0; d < 4; ++d) {
            float a = toz_b[d];
            #pragma unroll
            for (int i = 0; i < 16; ++i) a = fmaf(P[16*k+i], toz_w[4*i+d], a);
            z[4*k+d] = a;
        }
    }
    #pragma unroll
    for (int i = 0; i < 8; ++i) out_z[8*g+i] = z[i];

    #pragma unroll
    for (int j = 0; j < 32; ++j) {
        float a = bridge_b[j];
        #pragma unroll
        for (int i = 0; i < 8; ++i) a = fmaf(z[i], bridge_w[32*i+j], a);
        out_recon[32*g+j] = a;
    }

    float d0 = z[0]-z[4], d1 = z[1]-z[5];
    float dd = sqrtf(d0*d0 + d1*d1 + 1e-6f);

    float V = vp_b2[0];
    float dV = 0.0f;
    #pragma unroll
    for (int j = 0; j < 32; ++j) {
        float w1 = vp_w1[j];
        float t  = fmaf(dd, w1, vp_b1[j]);
        float et = __expf(t);
        float sp = __logf(1.0f + et);
        float sg = et / (1.0f + et);
        float w2 = vp_w2[j];
        V  = fmaf(sp, w2, V);
        dV = fmaf(sg * w1, w2, dV);
    }
    out_V[g] = V;

    float scale = dV / dd;
    float gx = scale * d0, gy = scale * d1;
    out_forces[4*g+0] = -gx;
    out_forces[4*g+1] = -gy;
    out_forces[4*g+2] =  gx;
    out_forces[4*g+3] =  gy;
}

// ---------------------------------------------------------------------------
extern "C" void kernel_launch(void* const* d_in, const int* in_sizes, int n_in,
                              void* d_out, int out_size, void* d_ws, size_t ws_size,
                              hipStream_t stream) {
    const float* x        = (const float*)d_in[0];
    const float* pos      = (const float*)d_in[1];
    const int*   ei       = (const int*)  d_in[2];
    const int*   batch    = (const int*)  d_in[3];
    const float* enc_w1   = (const float*)d_in[4];
    const float* enc_b1   = (const float*)d_in[5];
    const float* enc_w2   = (const float*)d_in[6];
    const float* enc_b2   = (const float*)d_in[7];
    const float* pool_w   = (const float*)d_in[8];
    const float* pool_b   = (const float*)d_in[9];
    const float* toz_w    = (const float*)d_in[10];
    const float* toz_b    = (const float*)d_in[11];
    const float* vp_w1    = (const float*)d_in[12];
    const float* vp_b1    = (const float*)d_in[13];
    const float* vp_w2    = (const float*)d_in[14];
    const float* vp_b2    = (const float*)d_in[15];
    const float* bridge_w = (const float*)d_in[16];
    const float* bridge_b = (const float*)d_in[17];

    // workspace layout (4B units), ~33.8 MB; NO memset needed:
    // cnts fully overwritten by bin_pack; pooled zeroed by bin_pack blocks 0..31.
    int*   cnts   = (int*)d_ws;                              // 256*256
    float* pooled = (float*)d_ws + NBKT*NBLK;                // 32768
    int*   staged = (int*)d_ws + NBKT*NBLK + 32768;          // 256*256*112
    h8*    xp     = (h8*)(staged + (size_t)NBKT*NBLK*SEGCAP);// 262144 * 16B = 4MB

    float* out        = (float*)d_out;
    float* out_recon  = out;                        // 1024*32
    float* out_z      = out_recon + 1024*32;        // 1024*8
    float* out_s      = out_z + 1024*8;             // 262144*2
    float* out_forces = out_s + (size_t)N_NODES*2;  // 1024*4
    float* out_V      = out_forces + 1024*4;        // 1024

    bin_pack_kernel<<<NBLK, 1024, 0, stream>>>(ei, x, pos, cnts, staged, xp, pooled);
    fused_node_kernel<<<NBKT, 1024, 0, stream>>>(
        xp, cnts, staged, batch,
        enc_w1, enc_b1, enc_w2, enc_b2, pool_w, pool_b, out_s, pooled);
    graph_kernel<<<NUM_GRAPHS/256, 256, 0, stream>>>(
        pooled, toz_w, toz_b, vp_w1, vp_b1, vp_w2, vp_b2,
        bridge_w, bridge_b, out_recon, out_z, out_forces, out_V);
}

// Round 15
// 208.825 us; speedup vs baseline: 1.5786x; 1.0155x over previous
//
#include <hip/hip_runtime.h>
#include <math.h>

#define N_NODES   262144
#define N_EDGES   4194304
#define NUM_GRAPHS 1024
#define NBKT      256          // buckets (dst >> 10), 1024 nodes each
#define BNODE     1024         // nodes per fused block (full bucket)
#define CAPK      17408        // bucket total capacity for esrc (mean 16384, +8 sigma)
#define NBLK      256          // bin_pack blocks
#define EPB       16384        // edges per bin_pack block
#define SEGCAP    112          // per-(bucket,block) segment cap (mean 64, +6 sigma)

typedef _Float16 h8 __attribute__((ext_vector_type(8)));

static __device__ __forceinline__ float fast_rcp(float v) {
    return __builtin_amdgcn_rcpf(v);
}

// ---------------------------------------------------------------------------
// K1: binning v4 (r14, byte-identical): deterministic fixed segments, no
// global cursor, no memset; fp16 record packing fused in.
// ---------------------------------------------------------------------------
__global__ __launch_bounds__(1024) void bin_pack_kernel(
    const int* __restrict__ ei, const float* __restrict__ x,
    const float* __restrict__ pos,
    int* __restrict__ cnts, int* __restrict__ staged,
    h8* __restrict__ xp, float* __restrict__ pooled)
{
    __shared__ int cnt[NBKT], rcnt[NBKT], lbase[NBKT];
    __shared__ int wsum[4];
    __shared__ int stage[EPB];                 // 64 KB
    int tid = threadIdx.x;
    if (tid < NBKT) { cnt[tid] = 0; rcnt[tid] = 0; }
    __syncthreads();

    // ---- pack 1024 nodes (1/thread) as fp16 records; zero pooled ----
    {
        int n0 = blockIdx.x * 1024 + tid;
        float4 xv = *(const float4*)(x + 4*n0);
        h8 o;
        o[0] = (_Float16)xv.x; o[1] = (_Float16)xv.y;
        o[2] = (_Float16)xv.z; o[3] = (_Float16)xv.w;
        o[4] = (_Float16)pos[3*n0+0]; o[5] = (_Float16)pos[3*n0+1];
        o[6] = (_Float16)pos[3*n0+2]; o[7] = (_Float16)0.0f;
        xp[n0] = o;
        if (blockIdx.x < 32) pooled[blockIdx.x*1024 + tid] = 0.0f;
    }

    // ---- histogram (dst kept in regs for rank pass) ----
    int base = blockIdx.x * EPB;
    const int4* d4 = (const int4*)(ei + N_EDGES + base);
    const int4* s4 = (const int4*)(ei + base);
    int4 dv[4];
    #pragma unroll
    for (int i = 0; i < 4; ++i) {
        dv[i] = d4[i*1024 + tid];
        atomicAdd(&cnt[dv[i].x >> 10], 1);
        atomicAdd(&cnt[dv[i].y >> 10], 1);
        atomicAdd(&cnt[dv[i].z >> 10], 1);
        atomicAdd(&cnt[dv[i].w >> 10], 1);
    }
    __syncthreads();

    // ---- local exclusive scan over 256 bins ----
    int lane = tid & 63, wid = tid >> 6;
    if (tid < NBKT) {
        int inc = cnt[tid];
        #pragma unroll
        for (int o = 1; o < 64; o <<= 1) {
            int t = __shfl_up(inc, o);
            if (lane >= o) inc += t;
        }
        if (lane == 63) wsum[wid] = inc;
        cnt[tid] = inc;                        // stash inclusive scan
    }
    __syncthreads();
    if (tid < NBKT) {
        int inc  = cnt[tid];
        int prev = __shfl_up(inc, 1);
        int excl = (lane == 0) ? 0 : prev;
        int wb = 0;
        #pragma unroll
        for (int w = 0; w < 4; ++w) if (w < wid) wb += wsum[w];
        lbase[tid] = wb + excl;
    }
    __syncthreads();

    // ---- rank + stage: ((dst&1023)<<18) | src ----
    #pragma unroll
    for (int i = 0; i < 4; ++i) {
        int4 sv = s4[i*1024 + tid];
        int d, s, bk, r;
        d = dv[i].x; s = sv.x; bk = d >> 10; r = atomicAdd(&rcnt[bk], 1);
        stage[lbase[bk] + r] = ((d & 1023) << 18) | s;
        d = dv[i].y; s = sv.y; bk = d >> 10; r = atomicAdd(&rcnt[bk], 1);
        stage[lbase[bk] + r] = ((d & 1023) << 18) | s;
        d = dv[i].z; s = sv.z; bk = d >> 10; r = atomicAdd(&rcnt[bk], 1);
        stage[lbase[bk] + r] = ((d & 1023) << 18) | s;
        d = dv[i].w; s = sv.w; bk = d >> 10; r = atomicAdd(&rcnt[bk], 1);
        stage[lbase[bk] + r] = ((d & 1023) << 18) | s;
    }
    __syncthreads();

    // ---- write-out to FIXED segments: 32 lanes/bin, 32 groups, 8 passes ----
    int sub = tid & 31, grp = tid >> 5;
    #pragma unroll
    for (int pass = 0; pass < NBKT/32; ++pass) {
        int bk  = pass*32 + grp;
        int c2  = rcnt[bk];
        int lb  = lbase[bk];
        if (c2 > SEGCAP) c2 = SEGCAP;          // deterministic input: never hit
        size_t sb = ((size_t)bk*NBLK + blockIdx.x)*SEGCAP;
        for (int k = sub; k < c2; k += 32)
            staged[sb + k] = stage[lb + k];
        if (sub == 0) cnts[bk*NBLK + blockIdx.x] = c2;
    }
}

// ---------------------------------------------------------------------------
// Per-edge contribution: rows 4..7 (x[src]) + row 8 (dist) of enc_w1, on top
// of the per-node precomputed hd[] (bias + dst rows). silu accumulate.
// ---------------------------------------------------------------------------
static __device__ __forceinline__ void edge_contrib(
    const float* __restrict__ sw1, const float* __restrict__ hd,
    float4 xs, float dist, float* __restrict__ acc)
{
    float h[16];
    #pragma unroll
    for (int j4 = 0; j4 < 4; ++j4) {
        float4 w = *(const float4*)&sw1[4*16 + 4*j4];
        h[4*j4+0] = fmaf(xs.x, w.x, hd[4*j4+0]);
        h[4*j4+1] = fmaf(xs.x, w.y, hd[4*j4+1]);
        h[4*j4+2] = fmaf(xs.x, w.z, hd[4*j4+2]);
        h[4*j4+3] = fmaf(xs.x, w.w, hd[4*j4+3]);
    }
    #pragma unroll
    for (int j4 = 0; j4 < 4; ++j4) {
        float4 w = *(const float4*)&sw1[5*16 + 4*j4];
        h[4*j4+0] = fmaf(xs.y, w.x, h[4*j4+0]);
        h[4*j4+1] = fmaf(xs.y, w.y, h[4*j4+1]);
        h[4*j4+2] = fmaf(xs.y, w.z, h[4*j4+2]);
        h[4*j4+3] = fmaf(xs.y, w.w, h[4*j4+3]);
    }
    #pragma unroll
    for (int j4 = 0; j4 < 4; ++j4) {
        float4 w = *(const float4*)&sw1[6*16 + 4*j4];
        h[4*j4+0] = fmaf(xs.z, w.x, h[4*j4+0]);
        h[4*j4+1] = fmaf(xs.z, w.y, h[4*j4+1]);
        h[4*j4+2] = fmaf(xs.z, w.z, h[4*j4+2]);
        h[4*j4+3] = fmaf(xs.z, w.w, h[4*j4+3]);
    }
    #pragma unroll
    for (int j4 = 0; j4 < 4; ++j4) {
        float4 w = *(const float4*)&sw1[7*16 + 4*j4];
        h[4*j4+0] = fmaf(xs.w, w.x, h[4*j4+0]);
        h[4*j4+1] = fmaf(xs.w, w.y, h[4*j4+1]);
        h[4*j4+2] = fmaf(xs.w, w.z, h[4*j4+2]);
        h[4*j4+3] = fmaf(xs.w, w.w, h[4*j4+3]);
    }
    #pragma unroll
    for (int j4 = 0; j4 < 4; ++j4) {
        float4 w = *(const float4*)&sw1[8*16 + 4*j4];
        h[4*j4+0] = fmaf(dist, w.x, h[4*j4+0]);
        h[4*j4+1] = fmaf(dist, w.y, h[4*j4+1]);
        h[4*j4+2] = fmaf(dist, w.z, h[4*j4+2]);
        h[4*j4+3] = fmaf(dist, w.w, h[4*j4+3]);
    }
    #pragma unroll
    for (int j = 0; j < 16; ++j) {
        float sg = fast_rcp(1.0f + __expf(-h[j]));
        acc[j] = fmaf(h[j], sg, acc[j]);
    }
}

// ---------------------------------------------------------------------------
// K2 (fused): r14 + DEGREE-SORTED edge loop. dg~Poisson(16) => wave runs
// E[max64]~27.6 iterations vs mean 16 = 1.7x divergence waste (the measured
// 46% VALUBusy at 2.4x the uniform-work estimate). A 64-bin degree sort
// (histogram+rank in LDS) lets Phase B process node perm[tid] so lanes in a
// wave have ~equal degree; acc[16] exchanged via 17-padded LDS accbuf back
// to original order for Phase C (node MLP + softmax + sorted-batch pooling
// unchanged). LDS ~151KB, still 1 block/CU.
// ---------------------------------------------------------------------------
__global__ __launch_bounds__(1024, 4) void fused_node_kernel(
    const h8* __restrict__ xp,
    const int* __restrict__ cnts, const int* __restrict__ staged,
    const int* __restrict__ batch,
    const float* __restrict__ w1, const float* __restrict__ b1,
    const float* __restrict__ w2, const float* __restrict__ b2,
    const float* __restrict__ pw, const float* __restrict__ pb,
    float* __restrict__ s_out, float* __restrict__ pooled)
{
    __shared__ int   esrc[CAPK];               // 69632 B
    __shared__ float accbuf[BNODE*17];         // 69632 B (17-pad: bank-safe)
    __shared__ int   ldeg[BNODE];              // hist -> cursor -> end offsets
    __shared__ int   rofs[BNODE];              // row start per node
    __shared__ int   perm[BNODE];              // degree-sorted node order
    __shared__ int   scnt[NBLK];
    __shared__ int   dhist[64];                // degree histogram / cursor
    __shared__ int   wsum[16];
    __shared__ __align__(16) float sw1[144];
    __shared__ float sb1[16];
    __shared__ __align__(16) float sw2[256];
    __shared__ float sb2[16];
    __shared__ float spw[32];
    __shared__ float spb[2];

    int tid = threadIdx.x;
    int bkt = blockIdx.x;
    if (tid < 144) sw1[tid] = w1[tid];
    if (tid >= 144 && tid < 160) sb1[tid - 144] = b1[tid - 144];
    if (tid >= 160 && tid < 176) sb2[tid - 160] = b2[tid - 160];
    if (tid >= 176 && tid < 208) spw[tid - 176] = pw[tid - 176];
    if (tid >= 208 && tid < 210) spb[tid - 208] = pb[tid - 208];
    if (tid >= 256 && tid < 512) sw2[tid - 256] = w2[tid - 256];
    if (tid >= 512 && tid < 768) scnt[tid - 512] = cnts[bkt*NBLK + (tid - 512)];
    if (tid >= 768 && tid < 832) dhist[tid - 768] = 0;
    ldeg[tid] = 0;
    __syncthreads();

    int lane = tid & 63, wid = tid >> 6;       // wid 0..15
    int nb0  = bkt * BNODE;

    // ---- Phase A1: histogram over 256 segments (wave-per-segment) ----
    for (int s = wid; s < NBLK; s += 16) {
        int c = scnt[s];
        const int* seg = staged + ((size_t)bkt*NBLK + s)*SEGCAP;
        for (int i = lane; i < c; i += 64)
            atomicAdd(&ldeg[seg[i] >> 18], 1);
    }
    __syncthreads();

    int dg  = ldeg[tid];                       // degree of node nb0+tid
    int inc = dg;
    #pragma unroll
    for (int o = 1; o < 64; o <<= 1) {
        int t = __shfl_up(inc, o);
        if (lane >= o) inc += t;
    }
    if (lane == 63) wsum[wid] = inc;
    __syncthreads();
    int wb = 0;
    #pragma unroll
    for (int w = 0; w < 16; ++w) if (w < wid) wb += wsum[w];
    int r0 = wb + inc - dg;                    // exclusive row offset in esrc
    rofs[tid] = r0;
    ldeg[tid] = r0;                            // reuse as scatter cursor
    __syncthreads();

    // ---- Phase A2: scatter src ids into esrc; degree-sort hist overlapped ----
    for (int s = wid; s < NBLK; s += 16) {
        int c = scnt[s];
        const int* seg = staged + ((size_t)bkt*NBLK + s)*SEGCAP;
        for (int i = lane; i < c; i += 64) {
            int p = seg[i];
            int r = atomicAdd(&ldeg[p >> 18], 1);
            if (r < CAPK) esrc[r] = p & 0x3FFFF;
        }
    }
    int db = dg < 63 ? dg : 63;
    atomicAdd(&dhist[db], 1);
    __syncthreads();

    // ---- degree-sort: exclusive scan of dhist (wave 0), then rank ----
    if (tid < 64) {
        int c  = dhist[tid];
        int i2 = c;
        #pragma unroll
        for (int o = 1; o < 64; o <<= 1) {
            int t2 = __shfl_up(i2, o);
            if (lane >= o) i2 += t2;
        }
        dhist[tid] = i2 - c;                   // exclusive base = cursor
    }
    __syncthreads();
    int rank = atomicAdd(&dhist[db], 1);
    perm[rank] = tid;
    __syncthreads();

    // ---- Phase B: per-node gather + edge MLP on v = perm[tid] ----
    int v   = perm[tid];
    int r0v = rofs[v];
    int dgv = ldeg[v] - r0v;                   // ldeg[v] advanced to end
    h8 rd = xp[nb0 + v];
    float4 xd = make_float4((float)rd[0], (float)rd[1], (float)rd[2], (float)rd[3]);
    float pdx = (float)rd[4], pdy = (float)rd[5], pdz = (float)rd[6];

    float hd[16];
    #pragma unroll
    for (int j = 0; j < 16; ++j) hd[j] = sb1[j];
    #pragma unroll
    for (int j4 = 0; j4 < 4; ++j4) {
        float4 w0 = *(const float4*)&sw1[0*16 + 4*j4];
        float4 w1r = *(const float4*)&sw1[1*16 + 4*j4];
        float4 w2r = *(const float4*)&sw1[2*16 + 4*j4];
        float4 w3r = *(const float4*)&sw1[3*16 + 4*j4];
        hd[4*j4+0] = fmaf(xd.x, w0.x, hd[4*j4+0]);
        hd[4*j4+1] = fmaf(xd.x, w0.y, hd[4*j4+1]);
        hd[4*j4+2] = fmaf(xd.x, w0.z, hd[4*j4+2]);
        hd[4*j4+3] = fmaf(xd.x, w0.w, hd[4*j4+3]);
        hd[4*j4+0] = fmaf(xd.y, w1r.x, hd[4*j4+0]);
        hd[4*j4+1] = fmaf(xd.y, w1r.y, hd[4*j4+1]);
        hd[4*j4+2] = fmaf(xd.y, w1r.z, hd[4*j4+2]);
        hd[4*j4+3] = fmaf(xd.y, w1r.w, hd[4*j4+3]);
        hd[4*j4+0] = fmaf(xd.z, w2r.x, hd[4*j4+0]);
        hd[4*j4+1] = fmaf(xd.z, w2r.y, hd[4*j4+1]);
        hd[4*j4+2] = fmaf(xd.z, w2r.z, hd[4*j4+2]);
        hd[4*j4+3] = fmaf(xd.z, w2r.w, hd[4*j4+3]);
        hd[4*j4+0] = fmaf(xd.w, w3r.x, hd[4*j4+0]);
        hd[4*j4+1] = fmaf(xd.w, w3r.y, hd[4*j4+1]);
        hd[4*j4+2] = fmaf(xd.w, w3r.z, hd[4*j4+2]);
        hd[4*j4+3] = fmaf(xd.w, w3r.w, hd[4*j4+3]);
    }

    float acc[16];
    #pragma unroll
    for (int j = 0; j < 16; ++j) acc[j] = 0.0f;

    int k = 0;
    for (; k + 2 <= dgv; k += 2) {
        int s0 = esrc[r0v + k];
        int s1 = esrc[r0v + k + 1];
        h8 e0 = xp[s0];
        h8 e1 = xp[s1];

        float4 a0 = make_float4((float)e0[0], (float)e0[1], (float)e0[2], (float)e0[3]);
        float dx0 = (float)e0[4] - pdx, dy0 = (float)e0[5] - pdy, dz0 = (float)e0[6] - pdz;
        float dist0 = sqrtf(fmaf(dx0, dx0, fmaf(dy0, dy0, dz0*dz0)));
        edge_contrib(sw1, hd, a0, dist0, acc);

        float4 a1 = make_float4((float)e1[0], (float)e1[1], (float)e1[2], (float)e1[3]);
        float dx1 = (float)e1[4] - pdx, dy1 = (float)e1[5] - pdy, dz1 = (float)e1[6] - pdz;
        float dist1 = sqrtf(fmaf(dx1, dx1, fmaf(dy1, dy1, dz1*dz1)));
        edge_contrib(sw1, hd, a1, dist1, acc);
    }
    if (k < dgv) {
        int s0 = esrc[r0v + k];
        h8 e0 = xp[s0];
        float4 a0 = make_float4((float)e0[0], (float)e0[1], (float)e0[2], (float)e0[3]);
        float dx0 = (float)e0[4] - pdx, dy0 = (float)e0[5] - pdy, dz0 = (float)e0[6] - pdz;
        float dist0 = sqrtf(fmaf(dx0, dx0, fmaf(dy0, dy0, dz0*dz0)));
        edge_contrib(sw1, hd, a0, dist0, acc);
    }

    // ---- exchange: acc back to original node order ----
    #pragma unroll
    for (int j = 0; j < 16; ++j) accbuf[v*17 + j] = acc[j];
    __syncthreads();

    // ---- Phase C: node MLP + softmax + pooling (original tid order) ----
    int n = nb0 + tid;
    int dgc = ldeg[tid] - rofs[tid];
    float c = (float)dgc;
    float inv = fast_rcp(fmaxf(c, 1.0f));
    float h[16];
    #pragma unroll
    for (int j = 0; j < 16; ++j) h[j] = c * sb2[j];
    #pragma unroll
    for (int i = 0; i < 16; ++i) {
        float f = accbuf[tid*17 + i];
        #pragma unroll
        for (int j4 = 0; j4 < 4; ++j4) {
            float4 w = *(const float4*)&sw2[i*16 + 4*j4];
            h[4*j4+0] = fmaf(f, w.x, h[4*j4+0]);
            h[4*j4+1] = fmaf(f, w.y, h[4*j4+1]);
            h[4*j4+2] = fmaf(f, w.z, h[4*j4+2]);
            h[4*j4+3] = fmaf(f, w.w, h[4*j4+3]);
        }
    }
    #pragma unroll
    for (int j = 0; j < 16; ++j) h[j] = fmaxf(h[j] * inv, 0.0f);

    float l0 = spb[0], l1 = spb[1];
    #pragma unroll
    for (int j = 0; j < 16; ++j) {
        l0 = fmaf(h[j], spw[2*j+0], l0);
        l1 = fmaf(h[j], spw[2*j+1], l1);
    }
    float m = fmaxf(l0, l1);
    float e0 = __expf(l0 - m), e1 = __expf(l1 - m);
    float r = fast_rcp(e0 + e1);
    float s0 = e0 * r, s1 = e1 * r;
    s_out[2*n+0] = s0;
    s_out[2*n+1] = s1;

    float w[32];
    #pragma unroll
    for (int j = 0; j < 16; ++j) { w[j] = s0 * h[j]; w[16+j] = s1 * h[j]; }

    int b = batch[n];
    #pragma unroll
    for (int o = 1; o < 64; o <<= 1) {
        int bn = __shfl_down(b, o);
        bool take = (lane + o < 64) && (bn == b);
        #pragma unroll
        for (int cc = 0; cc < 32; ++cc) {
            float vn = __shfl_down(w[cc], o);
            if (take) w[cc] += vn;
        }
    }
    int bp = __shfl_up(b, 1);
    if (lane == 0 || bp != b) {
        float* pg = pooled + 32*b;
        #pragma unroll
        for (int cc = 0; cc < 32; ++cc) unsafeAtomicAdd(pg + cc, w[cc]);
    }
}

// ---------------------------------------------------------------------------
// K3: per-graph heads. z, recon, analytic potential + forces.
// ---------------------------------------------------------------------------
__global__ __launch_bounds__(256) void graph_kernel(
    const float* __restrict__ pooled,
    const float* __restrict__ toz_w, const float* __restrict__ toz_b,
    const float* __restrict__ vp_w1, const float* __restrict__ vp_b1,
    const float* __restrict__ vp_w2, const float* __restrict__ vp_b2,
    const float* __restrict__ bridge_w, const float* __restrict__ bridge_b,
    float* __restrict__ out_recon, float* __restrict__ out_z,
    float* __restrict__ out_forces, float* __restrict__ out_V)
{
    int g = blockIdx.x * 256 + threadIdx.x;
    if (g >= NUM_GRAPHS) return;

    const float* P = pooled + 32*g;
    float z[8];
    #pragma unroll
    for (int k = 0; k < 2; ++k) {
        #pragma unroll
        for (int d = 0; d < 4; ++d) {
            float a = toz_b[d];
            #pragma unroll
            for (int i = 0; i < 16; ++i) a = fmaf(P[16*k+i], toz_w[4*i+d], a);
            z[4*k+d] = a;
        }
    }
    #pragma unroll
    for (int i = 0; i < 8; ++i) out_z[8*g+i] = z[i];

    #pragma unroll
    for (int j = 0; j < 32; ++j) {
        float a = bridge_b[j];
        #pragma unroll
        for (int i = 0; i < 8; ++i) a = fmaf(z[i], bridge_w[32*i+j], a);
        out_recon[32*g+j] = a;
    }

    float d0 = z[0]-z[4], d1 = z[1]-z[5];
    float dd = sqrtf(d0*d0 + d1*d1 + 1e-6f);

    float V = vp_b2[0];
    float dV = 0.0f;
    #pragma unroll
    for (int j = 0; j < 32; ++j) {
        float w1 = vp_w1[j];
        float t  = fmaf(dd, w1, vp_b1[j]);
        float et = __expf(t);
        float sp = __logf(1.0f + et);
        float sg = et / (1.0f + et);
        float w2 = vp_w2[j];
        V  = fmaf(sp, w2, V);
        dV = fmaf(sg * w1, w2, dV);
    }
    out_V[g] = V;

    float scale = dV / dd;
    float gx = scale * d0, gy = scale * d1;
    out_forces[4*g+0] = -gx;
    out_forces[4*g+1] = -gy;
    out_forces[4*g+2] =  gx;
    out_forces[4*g+3] =  gy;
}

// ---------------------------------------------------------------------------
extern "C" void kernel_launch(void* const* d_in, const int* in_sizes, int n_in,
                              void* d_out, int out_size, void* d_ws, size_t ws_size,
                              hipStream_t stream) {
    const float* x        = (const float*)d_in[0];
    const float* pos      = (const float*)d_in[1];
    const int*   ei       = (const int*)  d_in[2];
    const int*   batch    = (const int*)  d_in[3];
    const float* enc_w1   = (const float*)d_in[4];
    const float* enc_b1   = (const float*)d_in[5];
    const float* enc_w2   = (const float*)d_in[6];
    const float* enc_b2   = (const float*)d_in[7];
    const float* pool_w   = (const float*)d_in[8];
    const float* pool_b   = (const float*)d_in[9];
    const float* toz_w    = (const float*)d_in[10];
    const float* toz_b    = (const float*)d_in[11];
    const float* vp_w1    = (const float*)d_in[12];
    const float* vp_b1    = (const float*)d_in[13];
    const float* vp_w2    = (const float*)d_in[14];
    const float* vp_b2    = (const float*)d_in[15];
    const float* bridge_w = (const float*)d_in[16];
    const float* bridge_b = (const float*)d_in[17];

    // workspace layout (4B units), ~33.8 MB; no memset (cnts overwritten,
    // pooled zeroed in bin_pack).
    int*   cnts   = (int*)d_ws;                              // 256*256
    float* pooled = (float*)d_ws + NBKT*NBLK;                // 32768
    int*   staged = (int*)d_ws + NBKT*NBLK + 32768;          // 256*256*112
    h8*    xp     = (h8*)(staged + (size_t)NBKT*NBLK*SEGCAP);// 262144 * 16B = 4MB

    float* out        = (float*)d_out;
    float* out_recon  = out;                        // 1024*32
    float* out_z      = out_recon + 1024*32;        // 1024*8
    float* out_s      = out_z + 1024*8;             // 262144*2
    float* out_forces = out_s + (size_t)N_NODES*2;  // 1024*4
    float* out_V      = out_forces + 1024*4;        // 1024

    bin_pack_kernel<<<NBLK, 1024, 0, stream>>>(ei, x, pos, cnts, staged, xp, pooled);
    fused_node_kernel<<<NBKT, 1024, 0, stream>>>(
        xp, cnts, staged, batch,
        enc_w1, enc_b1, enc_w2, enc_b2, pool_w, pool_b, out_s, pooled);
    graph_kernel<<<NUM_GRAPHS/256, 256, 0, stream>>>(
        pooled, toz_w, toz_b, vp_w1, vp_b1, vp_w2, vp_b2,
        bridge_w, bridge_b, out_recon, out_z, out_forces, out_V);
}

// Round 16
// 206.909 us; speedup vs baseline: 1.5932x; 1.0093x over previous
//
#include <hip/hip_runtime.h>
#include <math.h>

#define N_NODES   262144
#define N_EDGES   4194304
#define NUM_GRAPHS 1024
#define NBKT      256          // buckets (dst >> 10), 1024 nodes each
#define BNODE     1024         // nodes per fused block (full bucket)
#define CAPK      17408        // bucket esrc capacity = 1024*17 (accbuf overlay)
#define NBLK      256          // bin_pack blocks
#define EPB       16384        // edges per bin_pack block
#define SEGCAP    112          // per-(bucket,block) segment cap (mean 64, +6 sigma)

typedef _Float16 h8 __attribute__((ext_vector_type(8)));

static __device__ __forceinline__ float fast_rcp(float v) {
    return __builtin_amdgcn_rcpf(v);
}

// ---------------------------------------------------------------------------
// K1: binning v4 (r14, byte-identical): deterministic fixed segments, no
// global cursor, no memset; fp16 record packing fused in.
// ---------------------------------------------------------------------------
__global__ __launch_bounds__(1024) void bin_pack_kernel(
    const int* __restrict__ ei, const float* __restrict__ x,
    const float* __restrict__ pos,
    int* __restrict__ cnts, int* __restrict__ staged,
    h8* __restrict__ xp, float* __restrict__ pooled)
{
    __shared__ int cnt[NBKT], rcnt[NBKT], lbase[NBKT];
    __shared__ int wsum[4];
    __shared__ int stage[EPB];                 // 64 KB
    int tid = threadIdx.x;
    if (tid < NBKT) { cnt[tid] = 0; rcnt[tid] = 0; }
    __syncthreads();

    // ---- pack 1024 nodes (1/thread) as fp16 records; zero pooled ----
    {
        int n0 = blockIdx.x * 1024 + tid;
        float4 xv = *(const float4*)(x + 4*n0);
        h8 o;
        o[0] = (_Float16)xv.x; o[1] = (_Float16)xv.y;
        o[2] = (_Float16)xv.z; o[3] = (_Float16)xv.w;
        o[4] = (_Float16)pos[3*n0+0]; o[5] = (_Float16)pos[3*n0+1];
        o[6] = (_Float16)pos[3*n0+2]; o[7] = (_Float16)0.0f;
        xp[n0] = o;
        if (blockIdx.x < 32) pooled[blockIdx.x*1024 + tid] = 0.0f;
    }

    // ---- histogram (dst kept in regs for rank pass) ----
    int base = blockIdx.x * EPB;
    const int4* d4 = (const int4*)(ei + N_EDGES + base);
    const int4* s4 = (const int4*)(ei + base);
    int4 dv[4];
    #pragma unroll
    for (int i = 0; i < 4; ++i) {
        dv[i] = d4[i*1024 + tid];
        atomicAdd(&cnt[dv[i].x >> 10], 1);
        atomicAdd(&cnt[dv[i].y >> 10], 1);
        atomicAdd(&cnt[dv[i].z >> 10], 1);
        atomicAdd(&cnt[dv[i].w >> 10], 1);
    }
    __syncthreads();

    // ---- local exclusive scan over 256 bins ----
    int lane = tid & 63, wid = tid >> 6;
    if (tid < NBKT) {
        int inc = cnt[tid];
        #pragma unroll
        for (int o = 1; o < 64; o <<= 1) {
            int t = __shfl_up(inc, o);
            if (lane >= o) inc += t;
        }
        if (lane == 63) wsum[wid] = inc;
        cnt[tid] = inc;                        // stash inclusive scan
    }
    __syncthreads();
    if (tid < NBKT) {
        int inc  = cnt[tid];
        int prev = __shfl_up(inc, 1);
        int excl = (lane == 0) ? 0 : prev;
        int wb = 0;
        #pragma unroll
        for (int w = 0; w < 4; ++w) if (w < wid) wb += wsum[w];
        lbase[tid] = wb + excl;
    }
    __syncthreads();

    // ---- rank + stage: ((dst&1023)<<18) | src ----
    #pragma unroll
    for (int i = 0; i < 4; ++i) {
        int4 sv = s4[i*1024 + tid];
        int d, s, bk, r;
        d = dv[i].x; s = sv.x; bk = d >> 10; r = atomicAdd(&rcnt[bk], 1);
        stage[lbase[bk] + r] = ((d & 1023) << 18) | s;
        d = dv[i].y; s = sv.y; bk = d >> 10; r = atomicAdd(&rcnt[bk], 1);
        stage[lbase[bk] + r] = ((d & 1023) << 18) | s;
        d = dv[i].z; s = sv.z; bk = d >> 10; r = atomicAdd(&rcnt[bk], 1);
        stage[lbase[bk] + r] = ((d & 1023) << 18) | s;
        d = dv[i].w; s = sv.w; bk = d >> 10; r = atomicAdd(&rcnt[bk], 1);
        stage[lbase[bk] + r] = ((d & 1023) << 18) | s;
    }
    __syncthreads();

    // ---- write-out to FIXED segments: 32 lanes/bin, 32 groups, 8 passes ----
    int sub = tid & 31, grp = tid >> 5;
    #pragma unroll
    for (int pass = 0; pass < NBKT/32; ++pass) {
        int bk  = pass*32 + grp;
        int c2  = rcnt[bk];
        int lb  = lbase[bk];
        if (c2 > SEGCAP) c2 = SEGCAP;          // deterministic input: never hit
        size_t sb = ((size_t)bk*NBLK + blockIdx.x)*SEGCAP;
        for (int k = sub; k < c2; k += 32)
            staged[sb + k] = stage[lb + k];
        if (sub == 0) cnts[bk*NBLK + blockIdx.x] = c2;
    }
}

// ---------------------------------------------------------------------------
// Per-edge contribution: rows 4..7 (x[src]) + row 8 (dist) of enc_w1, on top
// of the per-node precomputed hd[] (bias + dst rows). silu accumulate.
// ---------------------------------------------------------------------------
static __device__ __forceinline__ void edge_contrib(
    const float* __restrict__ sw1, const float* __restrict__ hd,
    float4 xs, float dist, float* __restrict__ acc)
{
    float h[16];
    #pragma unroll
    for (int j4 = 0; j4 < 4; ++j4) {
        float4 w = *(const float4*)&sw1[4*16 + 4*j4];
        h[4*j4+0] = fmaf(xs.x, w.x, hd[4*j4+0]);
        h[4*j4+1] = fmaf(xs.x, w.y, hd[4*j4+1]);
        h[4*j4+2] = fmaf(xs.x, w.z, hd[4*j4+2]);
        h[4*j4+3] = fmaf(xs.x, w.w, hd[4*j4+3]);
    }
    #pragma unroll
    for (int j4 = 0; j4 < 4; ++j4) {
        float4 w = *(const float4*)&sw1[5*16 + 4*j4];
        h[4*j4+0] = fmaf(xs.y, w.x, h[4*j4+0]);
        h[4*j4+1] = fmaf(xs.y, w.y, h[4*j4+1]);
        h[4*j4+2] = fmaf(xs.y, w.z, h[4*j4+2]);
        h[4*j4+3] = fmaf(xs.y, w.w, h[4*j4+3]);
    }
    #pragma unroll
    for (int j4 = 0; j4 < 4; ++j4) {
        float4 w = *(const float4*)&sw1[6*16 + 4*j4];
        h[4*j4+0] = fmaf(xs.z, w.x, h[4*j4+0]);
        h[4*j4+1] = fmaf(xs.z, w.y, h[4*j4+1]);
        h[4*j4+2] = fmaf(xs.z, w.z, h[4*j4+2]);
        h[4*j4+3] = fmaf(xs.z, w.w, h[4*j4+3]);
    }
    #pragma unroll
    for (int j4 = 0; j4 < 4; ++j4) {
        float4 w = *(const float4*)&sw1[7*16 + 4*j4];
        h[4*j4+0] = fmaf(xs.w, w.x, h[4*j4+0]);
        h[4*j4+1] = fmaf(xs.w, w.y, h[4*j4+1]);
        h[4*j4+2] = fmaf(xs.w, w.z, h[4*j4+2]);
        h[4*j4+3] = fmaf(xs.w, w.w, h[4*j4+3]);
    }
    #pragma unroll
    for (int j4 = 0; j4 < 4; ++j4) {
        float4 w = *(const float4*)&sw1[8*16 + 4*j4];
        h[4*j4+0] = fmaf(dist, w.x, h[4*j4+0]);
        h[4*j4+1] = fmaf(dist, w.y, h[4*j4+1]);
        h[4*j4+2] = fmaf(dist, w.z, h[4*j4+2]);
        h[4*j4+3] = fmaf(dist, w.w, h[4*j4+3]);
    }
    #pragma unroll
    for (int j = 0; j < 16; ++j) {
        float sg = fast_rcp(1.0f + __expf(-h[j]));
        acc[j] = fmaf(h[j], sg, acc[j]);
    }
}

// ---------------------------------------------------------------------------
// K2 (fused): r15 + LDS DIET -> 2 blocks/CU (32 waves). Phase B was gather-
// throughput bound: 2 loads in flight/lane x 16 waves/CU = 0.16 loads/cy at
// ~200cy L2 latency = ~43us for 16.4K gathers. Doubling waves doubles it.
// Diet: (1) esrc UNIONED with accbuf (dead after Phase B; CAPK=1024*17
// exactly), one extra barrier before overwrite; (2) rofs[] dropped -- perm
// packs (r0<<10)|tid. LDS 81.0KB < 81.9KB -> 2 blocks/CU.
// ---------------------------------------------------------------------------
__global__ __launch_bounds__(1024, 4) void fused_node_kernel(
    const h8* __restrict__ xp,
    const int* __restrict__ cnts, const int* __restrict__ staged,
    const int* __restrict__ batch,
    const float* __restrict__ w1, const float* __restrict__ b1,
    const float* __restrict__ w2, const float* __restrict__ b2,
    const float* __restrict__ pw, const float* __restrict__ pb,
    float* __restrict__ s_out, float* __restrict__ pooled)
{
    __shared__ union {
        int   esrc[CAPK];                      // Phase A/B
        float accbuf[CAPK];                    // Phase C (1024*17, bank-padded)
    } u;                                       // 69632 B
    __shared__ int   ldeg[BNODE];              // hist -> cursor -> end offsets
    __shared__ int   perm[BNODE];              // (r0<<10) | node
    __shared__ int   scnt[NBLK];
    __shared__ int   dhist[64];
    __shared__ int   wsum[16];
    __shared__ __align__(16) float sw1[144];
    __shared__ float sb1[16];
    __shared__ __align__(16) float sw2[256];
    __shared__ float sb2[16];
    __shared__ float spw[32];
    __shared__ float spb[2];

    int tid = threadIdx.x;
    int bkt = blockIdx.x;
    if (tid < 144) sw1[tid] = w1[tid];
    if (tid >= 144 && tid < 160) sb1[tid - 144] = b1[tid - 144];
    if (tid >= 160 && tid < 176) sb2[tid - 160] = b2[tid - 160];
    if (tid >= 176 && tid < 208) spw[tid - 176] = pw[tid - 176];
    if (tid >= 208 && tid < 210) spb[tid - 208] = pb[tid - 208];
    if (tid >= 256 && tid < 512) sw2[tid - 256] = w2[tid - 256];
    if (tid >= 512 && tid < 768) scnt[tid - 512] = cnts[bkt*NBLK + (tid - 512)];
    if (tid >= 768 && tid < 832) dhist[tid - 768] = 0;
    ldeg[tid] = 0;
    __syncthreads();

    int lane = tid & 63, wid = tid >> 6;       // wid 0..15
    int nb0  = bkt * BNODE;

    // ---- Phase A1: histogram over 256 segments (wave-per-segment) ----
    for (int s = wid; s < NBLK; s += 16) {
        int c = scnt[s];
        const int* seg = staged + ((size_t)bkt*NBLK + s)*SEGCAP;
        for (int i = lane; i < c; i += 64)
            atomicAdd(&ldeg[seg[i] >> 18], 1);
    }
    __syncthreads();

    int dg  = ldeg[tid];                       // degree of node nb0+tid
    int inc = dg;
    #pragma unroll
    for (int o = 1; o < 64; o <<= 1) {
        int t = __shfl_up(inc, o);
        if (lane >= o) inc += t;
    }
    if (lane == 63) wsum[wid] = inc;
    __syncthreads();
    int wb = 0;
    #pragma unroll
    for (int w = 0; w < 16; ++w) if (w < wid) wb += wsum[w];
    int r0 = wb + inc - dg;                    // exclusive row offset (register)
    ldeg[tid] = r0;                            // reuse as scatter cursor
    __syncthreads();

    // ---- Phase A2: scatter src ids into esrc; degree hist overlapped ----
    for (int s = wid; s < NBLK; s += 16) {
        int c = scnt[s];
        const int* seg = staged + ((size_t)bkt*NBLK + s)*SEGCAP;
        for (int i = lane; i < c; i += 64) {
            int p = seg[i];
            int r = atomicAdd(&ldeg[p >> 18], 1);
            if (r < CAPK) u.esrc[r] = p & 0x3FFFF;
        }
    }
    int db = dg < 63 ? dg : 63;
    atomicAdd(&dhist[db], 1);
    __syncthreads();

    // ---- degree-sort: exclusive scan of dhist (wave 0), then rank ----
    if (tid < 64) {
        int c  = dhist[tid];
        int i2 = c;
        #pragma unroll
        for (int o = 1; o < 64; o <<= 1) {
            int t2 = __shfl_up(i2, o);
            if (lane >= o) i2 += t2;
        }
        dhist[tid] = i2 - c;                   // exclusive base = cursor
    }
    __syncthreads();
    int rank = atomicAdd(&dhist[db], 1);
    perm[rank] = (r0 << 10) | tid;             // pack row start + node
    __syncthreads();

    // ---- Phase B: per-node gather + edge MLP on sorted node v ----
    int pk  = perm[tid];
    int v   = pk & 1023;
    int r0v = pk >> 10;
    int dgv = ldeg[v] - r0v;                   // ldeg[v] advanced to end
    h8 rd = xp[nb0 + v];
    float4 xd = make_float4((float)rd[0], (float)rd[1], (float)rd[2], (float)rd[3]);
    float pdx = (float)rd[4], pdy = (float)rd[5], pdz = (float)rd[6];

    float hd[16];
    #pragma unroll
    for (int j = 0; j < 16; ++j) hd[j] = sb1[j];
    #pragma unroll
    for (int j4 = 0; j4 < 4; ++j4) {
        float4 w0 = *(const float4*)&sw1[0*16 + 4*j4];
        float4 w1r = *(const float4*)&sw1[1*16 + 4*j4];
        float4 w2r = *(const float4*)&sw1[2*16 + 4*j4];
        float4 w3r = *(const float4*)&sw1[3*16 + 4*j4];
        hd[4*j4+0] = fmaf(xd.x, w0.x, hd[4*j4+0]);
        hd[4*j4+1] = fmaf(xd.x, w0.y, hd[4*j4+1]);
        hd[4*j4+2] = fmaf(xd.x, w0.z, hd[4*j4+2]);
        hd[4*j4+3] = fmaf(xd.x, w0.w, hd[4*j4+3]);
        hd[4*j4+0] = fmaf(xd.y, w1r.x, hd[4*j4+0]);
        hd[4*j4+1] = fmaf(xd.y, w1r.y, hd[4*j4+1]);
        hd[4*j4+2] = fmaf(xd.y, w1r.z, hd[4*j4+2]);
        hd[4*j4+3] = fmaf(xd.y, w1r.w, hd[4*j4+3]);
        hd[4*j4+0] = fmaf(xd.z, w2r.x, hd[4*j4+0]);
        hd[4*j4+1] = fmaf(xd.z, w2r.y, hd[4*j4+1]);
        hd[4*j4+2] = fmaf(xd.z, w2r.z, hd[4*j4+2]);
        hd[4*j4+3] = fmaf(xd.z, w2r.w, hd[4*j4+3]);
        hd[4*j4+0] = fmaf(xd.w, w3r.x, hd[4*j4+0]);
        hd[4*j4+1] = fmaf(xd.w, w3r.y, hd[4*j4+1]);
        hd[4*j4+2] = fmaf(xd.w, w3r.z, hd[4*j4+2]);
        hd[4*j4+3] = fmaf(xd.w, w3r.w, hd[4*j4+3]);
    }

    float acc[16];
    #pragma unroll
    for (int j = 0; j < 16; ++j) acc[j] = 0.0f;

    int k = 0;
    for (; k + 2 <= dgv; k += 2) {
        int s0 = u.esrc[r0v + k];
        int s1 = u.esrc[r0v + k + 1];
        h8 e0 = xp[s0];
        h8 e1 = xp[s1];

        float4 a0 = make_float4((float)e0[0], (float)e0[1], (float)e0[2], (float)e0[3]);
        float dx0 = (float)e0[4] - pdx, dy0 = (float)e0[5] - pdy, dz0 = (float)e0[6] - pdz;
        float dist0 = sqrtf(fmaf(dx0, dx0, fmaf(dy0, dy0, dz0*dz0)));
        edge_contrib(sw1, hd, a0, dist0, acc);

        float4 a1 = make_float4((float)e1[0], (float)e1[1], (float)e1[2], (float)e1[3]);
        float dx1 = (float)e1[4] - pdx, dy1 = (float)e1[5] - pdy, dz1 = (float)e1[6] - pdz;
        float dist1 = sqrtf(fmaf(dx1, dx1, fmaf(dy1, dy1, dz1*dz1)));
        edge_contrib(sw1, hd, a1, dist1, acc);
    }
    if (k < dgv) {
        int s0 = u.esrc[r0v + k];
        h8 e0 = xp[s0];
        float4 a0 = make_float4((float)e0[0], (float)e0[1], (float)e0[2], (float)e0[3]);
        float dx0 = (float)e0[4] - pdx, dy0 = (float)e0[5] - pdy, dz0 = (float)e0[6] - pdz;
        float dist0 = sqrtf(fmaf(dx0, dx0, fmaf(dy0, dy0, dz0*dz0)));
        edge_contrib(sw1, hd, a0, dist0, acc);
    }
    __syncthreads();                           // all esrc reads done

    // ---- exchange: acc back to original node order via accbuf overlay ----
    #pragma unroll
    for (int j = 0; j < 16; ++j) u.accbuf[v*17 + j] = acc[j];
    __syncthreads();

    // ---- Phase C: node MLP + softmax + pooling (original tid order) ----
    int n = nb0 + tid;
    int dgc = ldeg[tid] - r0;                  // end - start (r0 in register)
    float c = (float)dgc;
    float inv = fast_rcp(fmaxf(c, 1.0f));
    float h[16];
    #pragma unroll
    for (int j = 0; j < 16; ++j) h[j] = c * sb2[j];
    #pragma unroll
    for (int i = 0; i < 16; ++i) {
        float f = u.accbuf[tid*17 + i];
        #pragma unroll
        for (int j4 = 0; j4 < 4; ++j4) {
            float4 w = *(const float4*)&sw2[i*16 + 4*j4];
            h[4*j4+0] = fmaf(f, w.x, h[4*j4+0]);
            h[4*j4+1] = fmaf(f, w.y, h[4*j4+1]);
            h[4*j4+2] = fmaf(f, w.z, h[4*j4+2]);
            h[4*j4+3] = fmaf(f, w.w, h[4*j4+3]);
        }
    }
    #pragma unroll
    for (int j = 0; j < 16; ++j) h[j] = fmaxf(h[j] * inv, 0.0f);

    float l0 = spb[0], l1 = spb[1];
    #pragma unroll
    for (int j = 0; j < 16; ++j) {
        l0 = fmaf(h[j], spw[2*j+0], l0);
        l1 = fmaf(h[j], spw[2*j+1], l1);
    }
    float m = fmaxf(l0, l1);
    float e0 = __expf(l0 - m), e1 = __expf(l1 - m);
    float r = fast_rcp(e0 + e1);
    float s0 = e0 * r, s1 = e1 * r;
    s_out[2*n+0] = s0;
    s_out[2*n+1] = s1;

    float w[32];
    #pragma unroll
    for (int j = 0; j < 16; ++j) { w[j] = s0 * h[j]; w[16+j] = s1 * h[j]; }

    int b = batch[n];
    #pragma unroll
    for (int o = 1; o < 64; o <<= 1) {
        int bn = __shfl_down(b, o);
        bool take = (lane + o < 64) && (bn == b);
        #pragma unroll
        for (int cc = 0; cc < 32; ++cc) {
            float vn = __shfl_down(w[cc], o);
            if (take) w[cc] += vn;
        }
    }
    int bp = __shfl_up(b, 1);
    if (lane == 0 || bp != b) {
        float* pg = pooled + 32*b;
        #pragma unroll
        for (int cc = 0; cc < 32; ++cc) unsafeAtomicAdd(pg + cc, w[cc]);
    }
}

// ---------------------------------------------------------------------------
// K3: per-graph heads. z, recon, analytic potential + forces.
// ---------------------------------------------------------------------------
__global__ __launch_bounds__(256) void graph_kernel(
    const float* __restrict__ pooled,
    const float* __restrict__ toz_w, const float* __restrict__ toz_b,
    const float* __restrict__ vp_w1, const float* __restrict__ vp_b1,
    const float* __restrict__ vp_w2, const float* __restrict__ vp_b2,
    const float* __restrict__ bridge_w, const float* __restrict__ bridge_b,
    float* __restrict__ out_recon, float* __restrict__ out_z,
    float* __restrict__ out_forces, float* __restrict__ out_V)
{
    int g = blockIdx.x * 256 + threadIdx.x;
    if (g >= NUM_GRAPHS) return;

    const float* P = pooled + 32*g;
    float z[8];
    #pragma unroll
    for (int k = 0; k < 2; ++k) {
        #pragma unroll
        for (int d = 0; d < 4; ++d) {
            float a = toz_b[d];
            #pragma unroll
            for (int i = 0; i < 16; ++i) a = fmaf(P[16*k+i], toz_w[4*i+d], a);
            z[4*k+d] = a;
        }
    }
    #pragma unroll
    for (int i = 0; i < 8; ++i) out_z[8*g+i] = z[i];

    #pragma unroll
    for (int j = 0; j < 32; ++j) {
        float a = bridge_b[j];
        #pragma unroll
        for (int i = 0; i < 8; ++i) a = fmaf(z[i], bridge_w[32*i+j], a);
        out_recon[32*g+j] = a;
    }

    float d0 = z[0]-z[4], d1 = z[1]-z[5];
    float dd = sqrtf(d0*d0 + d1*d1 + 1e-6f);

    float V = vp_b2[0];
    float dV = 0.0f;
    #pragma unroll
    for (int j = 0; j < 32; ++j) {
        float w1 = vp_w1[j];
        float t  = fmaf(dd, w1, vp_b1[j]);
        float et = __expf(t);
        float sp = __logf(1.0f + et);
        float sg = et / (1.0f + et);
        float w2 = vp_w2[j];
        V  = fmaf(sp, w2, V);
        dV = fmaf(sg * w1, w2, dV);
    }
    out_V[g] = V;

    float scale = dV / dd;
    float gx = scale * d0, gy = scale * d1;
    out_forces[4*g+0] = -gx;
    out_forces[4*g+1] = -gy;
    out_forces[4*g+2] =  gx;
    out_forces[4*g+3] =  gy;
}

// ---------------------------------------------------------------------------
extern "C" void kernel_launch(void* const* d_in, const int* in_sizes, int n_in,
                              void* d_out, int out_size, void* d_ws, size_t ws_size,
                              hipStream_t stream) {
    const float* x        = (const float*)d_in[0];
    const float* pos      = (const float*)d_in[1];
    const int*   ei       = (const int*)  d_in[2];
    const int*   batch    = (const int*)  d_in[3];
    const float* enc_w1   = (const float*)d_in[4];
    const float* enc_b1   = (const float*)d_in[5];
    const float* enc_w2   = (const float*)d_in[6];
    const float* enc_b2   = (const float*)d_in[7];
    const float* pool_w   = (const float*)d_in[8];
    const float* pool_b   = (const float*)d_in[9];
    const float* toz_w    = (const float*)d_in[10];
    const float* toz_b    = (const float*)d_in[11];
    const float* vp_w1    = (const float*)d_in[12];
    const float* vp_b1    = (const float*)d_in[13];
    const float* vp_w2    = (const float*)d_in[14];
    const float* vp_b2    = (const float*)d_in[15];
    const float* bridge_w = (const float*)d_in[16];
    const float* bridge_b = (const float*)d_in[17];

    // workspace layout (4B units), ~33.8 MB; no memset (cnts overwritten,
    // pooled zeroed in bin_pack).
    int*   cnts   = (int*)d_ws;                              // 256*256
    float* pooled = (float*)d_ws + NBKT*NBLK;                // 32768
    int*   staged = (int*)d_ws + NBKT*NBLK + 32768;          // 256*256*112
    h8*    xp     = (h8*)(staged + (size_t)NBKT*NBLK*SEGCAP);// 262144 * 16B = 4MB

    float* out        = (float*)d_out;
    float* out_recon  = out;                        // 1024*32
    float* out_z      = out_recon + 1024*32;        // 1024*8
    float* out_s      = out_z + 1024*8;             // 262144*2
    float* out_forces = out_s + (size_t)N_NODES*2;  // 1024*4
    float* out_V      = out_forces + 1024*4;        // 1024

    bin_pack_kernel<<<NBLK, 1024, 0, stream>>>(ei, x, pos, cnts, staged, xp, pooled);
    fused_node_kernel<<<NBKT, 1024, 0, stream>>>(
        xp, cnts, staged, batch,
        enc_w1, enc_b1, enc_w2, enc_b2, pool_w, pool_b, out_s, pooled);
    graph_kernel<<<NUM_GRAPHS/256, 256, 0, stream>>>(
        pooled, toz_w, toz_b, vp_w1, vp_b1, vp_w2, vp_b2,
        bridge_w, bridge_b, out_recon, out_z, out_forces, out_V);
}